// Round 1
// 2521.328 us; speedup vs baseline: 1.6843x; 1.6843x over previous
//
#include <hip/hip_runtime.h>
#include <hip/hip_bf16.h>

#define NN 10000
#define NE 80000
#define PP 4
#define CC 128
#define NR (NN*PP)   // 40000 node rows
#define ER (NE*PP)   // 320000 edge rows
#define S1 136       // LDS row stride (u16) for bf16 K=128 rows: 68 dwords == 4 mod 32; 17 quads -> conflict-free b128

typedef unsigned short u16;
typedef unsigned int   u32;
typedef __attribute__((ext_vector_type(8))) short short8;   // 8 bf16 (4 VGPRs) MFMA A/B frag
typedef __attribute__((ext_vector_type(4))) float f32x4;    // MFMA C/D frag

__device__ inline float b2f(u16 v) { return __uint_as_float(((u32)v) << 16); }
__device__ inline float bfl(u32 u) { return __uint_as_float(u << 16); }
__device__ inline float bfh(u32 u) { return __uint_as_float(u & 0xffff0000u); }
__device__ inline u16 f2b(float f) {
    u32 x = __float_as_uint(f);
    return (u16)((x + 0x7fffu + ((x >> 16) & 1u)) >> 16);
}
__device__ inline void atomicMaxF(float* addr, float val) {
    if (val >= 0.f) atomicMax((int*)addr, __float_as_int(val));
    else            atomicMin((u32*)addr, __float_as_uint(val));
}
__device__ inline f32x4 mfma16(short8 a, short8 b, f32x4 c) {
    return __builtin_amdgcn_mfma_f32_16x16x32_bf16(a, b, c, 0, 0, 0);
}

// acc = sum_k x[k] * WTrow[k], K=128, bf16 weight row in LDS
__device__ inline float mv128(const u16* WTrow, const float* x) {
    const uint4* w4 = (const uint4*)WTrow;
    float acc = 0.f;
#pragma unroll
    for (int j = 0; j < 16; ++j) {
        uint4 w = w4[j];
        const float* p = x + 8 * j;
        acc += p[0]*bfl(w.x) + p[1]*bfh(w.x) + p[2]*bfl(w.y) + p[3]*bfh(w.y)
             + p[4]*bfl(w.z) + p[5]*bfh(w.z) + p[6]*bfl(w.w) + p[7]*bfh(w.w);
    }
    return acc;
}
__device__ inline void mv128x2(const u16* WTrow, const float* x0, const float* x1,
                               float& a0, float& a1) {
    const uint4* w4 = (const uint4*)WTrow;
    float acc0 = 0.f, acc1 = 0.f;
#pragma unroll
    for (int j = 0; j < 16; ++j) {
        uint4 w = w4[j];
        float w0=bfl(w.x), w1=bfh(w.x), w2=bfl(w.y), w3=bfh(w.y);
        float w4f=bfl(w.z), w5=bfh(w.z), w6=bfl(w.w), w7=bfh(w.w);
        const float* p0 = x0 + 8 * j; const float* p1 = x1 + 8 * j;
        acc0 += p0[0]*w0 + p0[1]*w1 + p0[2]*w2 + p0[3]*w3 + p0[4]*w4f + p0[5]*w5 + p0[6]*w6 + p0[7]*w7;
        acc1 += p1[0]*w0 + p1[1]*w1 + p1[2]*w2 + p1[3]*w3 + p1[4]*w4f + p1[5]*w5 + p1[6]*w6 + p1[7]*w7;
    }
    a0 = acc0; a1 = acc1;
}
__device__ inline float mv256(const u16* WTrow, const float* x) {
    const uint4* w4 = (const uint4*)WTrow;
    float acc = 0.f;
#pragma unroll
    for (int j = 0; j < 32; ++j) {
        uint4 w = w4[j];
        const float* p = x + 8 * j;
        acc += p[0]*bfl(w.x) + p[1]*bfh(w.x) + p[2]*bfl(w.y) + p[3]*bfh(w.y)
             + p[4]*bfl(w.z) + p[5]*bfh(w.z) + p[6]*bfl(w.w) + p[7]*bfh(w.w);
    }
    return acc;
}

// ---------------- kernel 1: [Q|K|V|Qe] = h @ [Wq|Wk|Wv|eWq], f32 out ----------------
__global__ __launch_bounds__(512) void k_qkvqe(const float* __restrict__ h,
    const float* __restrict__ Wq, const float* __restrict__ Wk,
    const float* __restrict__ Wv, const float* __restrict__ eWq,
    float* __restrict__ out)
{
    __shared__ __align__(16) u16 WT[512 * S1];
    __shared__ float xs[2][128];
    const int t = threadIdx.x;
    {
        int sel = t >> 7, col = t & 127;
        const float* W = (sel == 0) ? Wq : (sel == 1) ? Wk : (sel == 2) ? Wv : eWq;
        u16* dp = &WT[t * S1];
        for (int k = 0; k < 128; ++k) dp[k] = f2b(W[k * 128 + col]);
    }
    __syncthreads();
    for (int base = blockIdx.x * 2; base < NR; base += gridDim.x * 2) {
        if (t < 256) xs[t >> 7][t & 127] = h[(base + (t >> 7)) * 128 + (t & 127)];
        __syncthreads();
        float a0, a1;
        mv128x2(&WT[t * S1], xs[0], xs[1], a0, a1);
        out[base * 512 + t] = a0;
        out[(base + 1) * 512 + t] = a1;
        __syncthreads();
    }
}

// ---------------- kernel 2: attention edges + fused Oe projection + BN-e stats ----------------
__global__ __launch_bounds__(256) void k_attn(const float* __restrict__ e,
    const int* __restrict__ src, const int* __restrict__ dst,
    const float* __restrict__ We, const float* __restrict__ Oe_w, const float* __restrict__ Oe_b,
    const float* __restrict__ qkvqe, float* __restrict__ wV, float* __restrict__ z,
    float* __restrict__ stats, float* __restrict__ out_e)
{
    __shared__ __align__(16) u16 WT[2 * 128 * S1];  // [0..127]=WeT, [128..255]=OeT
    __shared__ float es[2][128];
    __shared__ float sc[2][128];
    __shared__ float sh[2][8];
    const int t = threadIdx.x;
    {
        int sel = t >> 7, col = t & 127;
        const float* W = sel ? Oe_w : We;
        u16* dp = &WT[(sel * 128 + col) * S1];
        for (int k = 0; k < 128; ++k) dp[k] = f2b(W[k * 128 + col]);
    }
    __syncthreads();
    const int rs = t >> 7, c = t & 127;
    const float oeb = Oe_b[c];
    float s1 = 0.f, s2 = 0.f;
    for (int base = blockIdx.x * 2; base < ER; base += gridDim.x * 2) {
        int re = base + rs;
        int ei = re >> 2, p = re & 3;
        int srow = src[ei] * 4 + p, drow = dst[ei] * 4 + p;
        es[rs][c] = e[re * 128 + c];
        __syncthreads();
        float pe = mv128(&WT[c * S1], es[rs]);  // proj_e = e @ We (this channel)
        float scv = qkvqe[srow * 512 + 128 + c] * qkvqe[drow * 512 + c] * 0.25f + pe;
        sc[rs][c] = scv;
        __syncthreads();
        if (c < 8) {
            float hs = 0.f;
#pragma unroll
            for (int d2 = 0; d2 < 16; ++d2) hs += sc[rs][c * 16 + d2];
            hs = fminf(fmaxf(hs, -5.f), 5.f);
            float sv = expf(hs);
            sh[rs][c] = sv;
            atomicAdd(&z[drow * 8 + c], sv);
        }
        __syncthreads();
        float sv = sh[rs][c >> 4];
        atomicAdd(&wV[drow * 128 + c], qkvqe[srow * 512 + 256 + c] * sv);
        float ef = es[rs][c] + oeb + mv128(&WT[(128 + c) * S1], sc[rs]);
        out_e[re * 128 + c] = ef;
        s1 += ef; s2 += ef * ef;
        __syncthreads();
    }
    atomicAdd(&stats[256 + c], s1);
    atomicAdd(&stats[384 + c], s2);
}

// ---------------- kernel 3: enhance edges via MFMA ----------------
// Tile: 64 edge rows x 128 cols. 512 threads = 8 waves, wave w owns head w (cols w*16..w*16+15).
// k_diff needs ~f32 precision (feeds norms + max winner): split-bf16 both sides,
//   k_diff = Ah*Wh + Al*Wh + Ah*Wl  (drops only lo*lo ~2^-18).
// v_diff / repe: A-side split (Ah+Al) x bf16 W  == baseline's f32-activation x bf16-weight profile.
__global__ __launch_bounds__(512) void k_enh(const float* __restrict__ h, const float* __restrict__ e,
    const int* __restrict__ src, const int* __restrict__ dst,
    const float* __restrict__ eWk, const float* __restrict__ eWv, const float* __restrict__ eWre,
    const float* __restrict__ qkvqe, float* __restrict__ henh)
{
    __shared__ __align__(16) u16 diffH[64 * S1];
    __shared__ __align__(16) u16 diffL[64 * S1];
    __shared__ __align__(16) u16 erH[64 * S1];
    __shared__ __align__(16) u16 erL[64 * S1];
    __shared__ int drowS[64];

    const int t = threadIdx.x;
    const int lane = t & 63;
    const int wid = t >> 6;          // wave id == head id (N-tile)
    const int lrow = lane & 15;      // A-row within M-tile / D-col within head
    const int lgrp = lane >> 4;      // 0..3

    // ---- load per-wave B fragments (weights) into VGPRs, once ----
    short8 wkh[4], wkl[4], wv8[4], wre8[4];
#pragma unroll
    for (int ks = 0; ks < 4; ++ks) {
        short8 a, b, c2, d2;
#pragma unroll
        for (int j = 0; j < 8; ++j) {
            int k = ks * 32 + lgrp * 8 + j;
            int idx = k * 128 + wid * 16 + lrow;
            float wk = eWk[idx];
            u16 hh = f2b(wk);
            a[j]  = (short)hh;
            b[j]  = (short)f2b(wk - b2f(hh));
            c2[j] = (short)f2b(eWv[idx]);
            d2[j] = (short)f2b(eWre[idx]);
        }
        wkh[ks] = a; wkl[ks] = b; wv8[ks] = c2; wre8[ks] = d2;
    }

    const int nTiles = ER / 64;  // 5000
    for (int tl = blockIdx.x; tl < nTiles; tl += gridDim.x) {
        const int rbase = tl * 64;
        // ---- stage tile: diff = relu(h[src]-h[dst]) and e rows, hi/lo bf16 ----
        {
            int r = t >> 3, c0 = (t & 7) * 16;
            int re = rbase + r, ei = re >> 2, p = re & 3;
            int sr = src[ei] * 4 + p, dr = dst[ei] * 4 + p;
            if ((t & 7) == 0) drowS[r] = dr;
            const float4* hs4 = (const float4*)(h + (size_t)sr * 128 + c0);
            const float4* hd4 = (const float4*)(h + (size_t)dr * 128 + c0);
            const float4* ee4 = (const float4*)(e + (size_t)re * 128 + c0);
            u32* dH = (u32*)(diffH + r * S1 + c0);
            u32* dL = (u32*)(diffL + r * S1 + c0);
            u32* eH = (u32*)(erH + r * S1 + c0);
            u32* eL = (u32*)(erL + r * S1 + c0);
#pragma unroll
            for (int q2 = 0; q2 < 4; ++q2) {
                float4 a = hs4[q2], b = hd4[q2], ev = ee4[q2];
                float d0 = fmaxf(a.x - b.x, 0.f), d1 = fmaxf(a.y - b.y, 0.f);
                float d2 = fmaxf(a.z - b.z, 0.f), d3 = fmaxf(a.w - b.w, 0.f);
                u16 h0 = f2b(d0), h1 = f2b(d1), h2 = f2b(d2), h3 = f2b(d3);
                dH[q2 * 2]     = (u32)h0 | ((u32)h1 << 16);
                dH[q2 * 2 + 1] = (u32)h2 | ((u32)h3 << 16);
                u16 l0 = f2b(d0 - b2f(h0)), l1 = f2b(d1 - b2f(h1));
                u16 l2 = f2b(d2 - b2f(h2)), l3 = f2b(d3 - b2f(h3));
                dL[q2 * 2]     = (u32)l0 | ((u32)l1 << 16);
                dL[q2 * 2 + 1] = (u32)l2 | ((u32)l3 << 16);
                u16 e0 = f2b(ev.x), e1 = f2b(ev.y), e2 = f2b(ev.z), e3 = f2b(ev.w);
                eH[q2 * 2]     = (u32)e0 | ((u32)e1 << 16);
                eH[q2 * 2 + 1] = (u32)e2 | ((u32)e3 << 16);
                u16 g0 = f2b(ev.x - b2f(e0)), g1 = f2b(ev.y - b2f(e1));
                u16 g2 = f2b(ev.z - b2f(e2)), g3 = f2b(ev.w - b2f(e3));
                eL[q2 * 2]     = (u32)g0 | ((u32)g1 << 16);
                eL[q2 * 2 + 1] = (u32)g2 | ((u32)g3 << 16);
            }
        }
        __syncthreads();

        // ---- MFMA + fused epilogue, per 16-row M-tile ----
#pragma unroll
        for (int mt = 0; mt < 4; ++mt) {
            f32x4 ak = {0.f, 0.f, 0.f, 0.f};
            f32x4 av = {0.f, 0.f, 0.f, 0.f};
            f32x4 ar = {0.f, 0.f, 0.f, 0.f};
#pragma unroll
            for (int ks = 0; ks < 4; ++ks) {
                const int off = (mt * 16 + lrow) * S1 + ks * 32 + lgrp * 8;
                short8 Ah = *(const short8*)(diffH + off);
                short8 Al = *(const short8*)(diffL + off);
                short8 Eh = *(const short8*)(erH + off);
                short8 El = *(const short8*)(erL + off);
                ak = mfma16(Ah, wkh[ks], ak);
                ak = mfma16(Al, wkh[ks], ak);
                ak = mfma16(Ah, wkl[ks], ak);
                av = mfma16(Ah, wv8[ks], av);
                av = mfma16(Al, wv8[ks], av);
                ar = mfma16(Eh, wre8[ks], ar);
                ar = mfma16(El, wre8[ks], ar);
            }
            // epilogue: norms (16-lane butterfly within head), score, msg, atomic max
#pragma unroll
            for (int q = 0; q < 4; ++q) {
                int rr = mt * 16 + lgrp * 4 + q;
                int dr = drowS[rr];
                float qd = qkvqe[(size_t)dr * 512 + 384 + wid * 16 + lrow];
                float kd = ak[q];
                float sk = kd * kd;
                sk += __shfl_xor(sk, 1); sk += __shfl_xor(sk, 2);
                sk += __shfl_xor(sk, 4); sk += __shfl_xor(sk, 8);
                float sq = qd * qd;
                sq += __shfl_xor(sq, 1); sq += __shfl_xor(sq, 2);
                sq += __shfl_xor(sq, 4); sq += __shfl_xor(sq, 8);
                float nk = sqrtf(sk + 1e-12f);
                float nq = sqrtf(sq + 1e-12f);
                float sc = qd * kd * (nk * nq + 1e-6f) + ar[q];
                float msg = sc * av[q];
                atomicMaxF(&henh[(size_t)dr * 128 + wid * 16 + lrow], msg);
            }
        }
        __syncthreads();
    }
}

// ---------------- kernel 4: combine h_attn + h_enh, Oh projection, residual, BN-h stats ----------------
__global__ __launch_bounds__(256) void k_comb(const float* __restrict__ h,
    const float* __restrict__ Oh_w, const float* __restrict__ Oh_b,
    const float* __restrict__ wV, const float* __restrict__ z, const float* __restrict__ henh,
    float* __restrict__ hf, float* __restrict__ stats)
{
    __shared__ __align__(16) u16 WT[128 * S1];
    __shared__ float xs[2][128];
    const int t = threadIdx.x;
    {
        int col = t & 127, half = t >> 7;
        for (int k = half * 64; k < half * 64 + 64; ++k) WT[col * S1 + k] = f2b(Oh_w[k * 128 + col]);
    }
    __syncthreads();
    const int rs = t >> 7, c = t & 127;
    const float ohb = Oh_b[c];
    float s1 = 0.f, s2 = 0.f;
    for (int base = blockIdx.x * 2; base < NR; base += gridDim.x * 2) {
        int r = base + rs;
        float hv = henh[r * 128 + c];
        u32 hb = __float_as_uint(hv);
        if (((hb >> 23) & 0xffu) == 0xffu) hv = 0.f;   // -inf/NaN (no in-edges) -> 0
        xs[rs][c] = wV[r * 128 + c] / (z[r * 8 + (c >> 4)] + 1e-6f) + hv;
        __syncthreads();
        float val = h[r * 128 + c] + ohb + mv128(&WT[c * S1], xs[rs]);
        hf[r * 128 + c] = val;
        s1 += val; s2 += val * val;
        __syncthreads();
    }
    atomicAdd(&stats[c], s1);
    atomicAdd(&stats[128 + c], s2);
}

// ---------------- kernel 5: BN scale/shift prep ----------------
__global__ void k_bnprep(const float* __restrict__ stats,
    const float* __restrict__ gh, const float* __restrict__ bh,
    const float* __restrict__ ge, const float* __restrict__ be, float* __restrict__ bnsc)
{
    int c = threadIdx.x;
    if (c < 128) {
        float m = stats[c] / (float)NR;
        float v = stats[128 + c] / (float)NR - m * m;
        float sc = gh[c] * rsqrtf(v + 1e-5f);
        bnsc[c] = sc; bnsc[128 + c] = bh[c] - m * sc;
        m = stats[256 + c] / (float)ER;
        v = stats[384 + c] / (float)ER - m * m;
        sc = ge[c] * rsqrtf(v + 1e-5f);
        bnsc[256 + c] = sc; bnsc[384 + c] = be[c] - m * sc;
    }
}

// ---------------- kernel 6: BN-h apply + FFN + residual -> out_h (f32) ----------------
__global__ __launch_bounds__(256) void k_ffn(const float* __restrict__ hf,
    const float* __restrict__ W1, const float* __restrict__ b1,
    const float* __restrict__ W2, const float* __restrict__ b2,
    const float* __restrict__ bnsc, float* __restrict__ out_h)
{
    __shared__ __align__(16) u16 W1T[256 * S1];
    __shared__ __align__(16) u16 W2T[128 * (2 * S1)];
    __shared__ float xn[128];
    __shared__ float tt[256];
    __shared__ float scs[128], shs[128];
    const int t = threadIdx.x;
    {
        for (int k = 0; k < 128; ++k) W1T[t * S1 + k] = f2b(W1[k * 256 + t]);
        int col = t & 127, half = t >> 7;
        for (int kk = 0; kk < 128; ++kk) { int k = half * 128 + kk; W2T[col * (2 * S1) + k] = f2b(W2[k * 128 + col]); }
        if (t < 128) { scs[t] = bnsc[t]; shs[t] = bnsc[128 + t]; }
    }
    __syncthreads();
    const float bb1 = b1[t];
    const float bb2 = (t < 128) ? b2[t] : 0.f;
    for (int r = blockIdx.x; r < NR; r += gridDim.x) {
        if (t < 128) xn[t] = hf[r * 128 + t] * scs[t] + shs[t];
        __syncthreads();
        tt[t] = fmaxf(bb1 + mv128(&W1T[t * S1], xn), 0.f);
        __syncthreads();
        if (t < 128) {
            float o = xn[t] + bb2 + mv256(&W2T[t * (2 * S1)], tt);
            out_h[r * 128 + t] = o;
        }
        __syncthreads();
    }
}

// ---------------- kernel 7: BN-e apply in place on d_out e-region (f32, float4) ----------------
__global__ __launch_bounds__(256) void k_bne(float* __restrict__ out_e, const float* __restrict__ bnsc)
{
    __shared__ float scs[128], shs[128];
    const int t = threadIdx.x;
    if (t < 128) { scs[t] = bnsc[256 + t]; shs[t] = bnsc[384 + t]; }
    __syncthreads();
    int idx = blockIdx.x * 256 + t;                // one float4 per thread
    const int total = ER * 128 / 4;                // 10,240,000
    for (; idx < total; idx += gridDim.x * 256) {
        float4 v = ((const float4*)out_e)[idx];
        int c0 = (idx * 4) & 127;
        v.x = v.x * scs[c0 + 0] + shs[c0 + 0];
        v.y = v.y * scs[c0 + 1] + shs[c0 + 1];
        v.z = v.z * scs[c0 + 2] + shs[c0 + 2];
        v.w = v.w * scs[c0 + 3] + shs[c0 + 3];
        ((float4*)out_e)[idx] = v;
    }
}

extern "C" void kernel_launch(void* const* d_in, const int* in_sizes, int n_in,
                              void* d_out, int out_size, void* d_ws, size_t ws_size,
                              hipStream_t stream)
{
    const float* h    = (const float*)d_in[0];
    const float* e    = (const float*)d_in[1];
    const int* src    = (const int*)d_in[2];
    const int* dst    = (const int*)d_in[3];
    const float* Wq   = (const float*)d_in[4];
    const float* Wk   = (const float*)d_in[5];
    const float* Wv   = (const float*)d_in[6];
    const float* We   = (const float*)d_in[7];
    const float* eWq  = (const float*)d_in[8];
    const float* eWk  = (const float*)d_in[9];
    const float* eWv  = (const float*)d_in[10];
    const float* eWre = (const float*)d_in[11];
    const float* Oh_w = (const float*)d_in[12];
    const float* Oh_b = (const float*)d_in[13];
    const float* Oe_w = (const float*)d_in[14];
    const float* Oe_b = (const float*)d_in[15];
    const float* bnhg = (const float*)d_in[16];
    const float* bnhb = (const float*)d_in[17];
    const float* bneg = (const float*)d_in[18];
    const float* bneb = (const float*)d_in[19];
    const float* W1   = (const float*)d_in[20];
    const float* b1   = (const float*)d_in[21];
    const float* W2   = (const float*)d_in[22];
    const float* b2   = (const float*)d_in[23];

    float* out_h = (float*)d_out;
    float* out_e = out_h + (size_t)NR * 128;

    char* w = (char*)d_ws;
    float* qkvqe = (float*)(w);                         // NR*512 f32  = 81,920,000 B
    float* wV    = (float*)(w + 81920000);              // NR*128 f32  = 20,480,000 B
    float* z     = (float*)(w + 102400000);             // NR*8  f32   =  1,280,000 B
    float* henh  = (float*)(w + 103680000);             // NR*128 f32  = 20,480,000 B
    float* hf    = (float*)(w + 124160000);             // NR*128 f32  = 20,480,000 B
    float* stats = (float*)(w + 144640000);             // 512 f32
    float* bnsc  = (float*)(w + 144642048);             // 512 f32

    hipMemsetAsync(wV,    0,    20480000, stream);
    hipMemsetAsync(z,     0,    1280000,  stream);
    hipMemsetAsync(stats, 0,    2048,     stream);
    hipMemsetAsync(henh,  0xFF, 20480000, stream);      // -NaN: identity for atomicMaxF, filtered by finite check

    k_qkvqe<<<256, 512, 0, stream>>>(h, Wq, Wk, Wv, eWq, qkvqe);
    k_attn <<<1024, 256, 0, stream>>>(e, src, dst, We, Oe_w, Oe_b, qkvqe, wV, z, stats, out_e);
    k_enh  <<<1024, 512, 0, stream>>>(h, e, src, dst, eWk, eWv, eWre, qkvqe, henh);
    k_comb <<<1024, 256, 0, stream>>>(h, Oh_w, Oh_b, wV, z, henh, hf, stats);
    k_bnprep<<<1, 128, 0, stream>>>(stats, bnhg, bnhb, bneg, bneb, bnsc);
    k_ffn  <<<256, 256, 0, stream>>>(hf, W1, b1, W2, b2, bnsc, out_h);
    k_bne  <<<40000, 256, 0, stream>>>(out_e, bnsc);
}

// Round 2
// 2052.992 us; speedup vs baseline: 2.0685x; 1.2281x over previous
//
#include <hip/hip_runtime.h>
#include <hip/hip_bf16.h>

#define NN 10000
#define NE 80000
#define PP 4
#define CC 128
#define NR (NN*PP)   // 40000 node rows
#define ER (NE*PP)   // 320000 edge rows
#define S1 136       // LDS row stride (u16) for bf16 K=128 rows: 68 dwords == 4 mod 32; 17 quads -> conflict-free b128

typedef unsigned short u16;
typedef unsigned int   u32;
typedef __attribute__((ext_vector_type(8))) short short8;   // 8 bf16 (4 VGPRs) MFMA A/B frag
typedef __attribute__((ext_vector_type(4))) float f32x4;    // MFMA C/D frag

__device__ inline float b2f(u16 v) { return __uint_as_float(((u32)v) << 16); }
__device__ inline float bfl(u32 u) { return __uint_as_float(u << 16); }
__device__ inline float bfh(u32 u) { return __uint_as_float(u & 0xffff0000u); }
__device__ inline u16 f2b(float f) {
    u32 x = __float_as_uint(f);
    return (u16)((x + 0x7fffu + ((x >> 16) & 1u)) >> 16);
}
__device__ inline void atomicMaxF(float* addr, float val) {
    if (val >= 0.f) atomicMax((int*)addr, __float_as_int(val));
    else            atomicMin((u32*)addr, __float_as_uint(val));
}
__device__ inline f32x4 mfma16(short8 a, short8 b, f32x4 c) {
    return __builtin_amdgcn_mfma_f32_16x16x32_bf16(a, b, c, 0, 0, 0);
}

// acc = sum_k x[k] * WTrow[k], K=128, bf16 weight row in LDS
__device__ inline float mv128(const u16* WTrow, const float* x) {
    const uint4* w4 = (const uint4*)WTrow;
    float acc = 0.f;
#pragma unroll
    for (int j = 0; j < 16; ++j) {
        uint4 w = w4[j];
        const float* p = x + 8 * j;
        acc += p[0]*bfl(w.x) + p[1]*bfh(w.x) + p[2]*bfl(w.y) + p[3]*bfh(w.y)
             + p[4]*bfl(w.z) + p[5]*bfh(w.z) + p[6]*bfl(w.w) + p[7]*bfh(w.w);
    }
    return acc;
}
__device__ inline void mv128x2(const u16* WTrow, const float* x0, const float* x1,
                               float& a0, float& a1) {
    const uint4* w4 = (const uint4*)WTrow;
    float acc0 = 0.f, acc1 = 0.f;
#pragma unroll
    for (int j = 0; j < 16; ++j) {
        uint4 w = w4[j];
        float w0=bfl(w.x), w1=bfh(w.x), w2=bfl(w.y), w3=bfh(w.y);
        float w4f=bfl(w.z), w5=bfh(w.z), w6=bfl(w.w), w7=bfh(w.w);
        const float* p0 = x0 + 8 * j; const float* p1 = x1 + 8 * j;
        acc0 += p0[0]*w0 + p0[1]*w1 + p0[2]*w2 + p0[3]*w3 + p0[4]*w4f + p0[5]*w5 + p0[6]*w6 + p0[7]*w7;
        acc1 += p1[0]*w0 + p1[1]*w1 + p1[2]*w2 + p1[3]*w3 + p1[4]*w4f + p1[5]*w5 + p1[6]*w6 + p1[7]*w7;
    }
    a0 = acc0; a1 = acc1;
}
__device__ inline float mv256(const u16* WTrow, const float* x) {
    const uint4* w4 = (const uint4*)WTrow;
    float acc = 0.f;
#pragma unroll
    for (int j = 0; j < 32; ++j) {
        uint4 w = w4[j];
        const float* p = x + 8 * j;
        acc += p[0]*bfl(w.x) + p[1]*bfh(w.x) + p[2]*bfl(w.y) + p[3]*bfh(w.y)
             + p[4]*bfl(w.z) + p[5]*bfh(w.z) + p[6]*bfl(w.w) + p[7]*bfh(w.w);
    }
    return acc;
}

// ---------------- kernel 1: [Q|K|V|Qe] = h @ [Wq|Wk|Wv|eWq], f32 out ----------------
__global__ __launch_bounds__(512) void k_qkvqe(const float* __restrict__ h,
    const float* __restrict__ Wq, const float* __restrict__ Wk,
    const float* __restrict__ Wv, const float* __restrict__ eWq,
    float* __restrict__ out)
{
    __shared__ __align__(16) u16 WT[512 * S1];
    __shared__ float xs[2][128];
    const int t = threadIdx.x;
    {
        int sel = t >> 7, col = t & 127;
        const float* W = (sel == 0) ? Wq : (sel == 1) ? Wk : (sel == 2) ? Wv : eWq;
        u16* dp = &WT[t * S1];
        for (int k = 0; k < 128; ++k) dp[k] = f2b(W[k * 128 + col]);
    }
    __syncthreads();
    for (int base = blockIdx.x * 2; base < NR; base += gridDim.x * 2) {
        if (t < 256) xs[t >> 7][t & 127] = h[(base + (t >> 7)) * 128 + (t & 127)];
        __syncthreads();
        float a0, a1;
        mv128x2(&WT[t * S1], xs[0], xs[1], a0, a1);
        out[base * 512 + t] = a0;
        out[(base + 1) * 512 + t] = a1;
        __syncthreads();
    }
}

// ---------------- kernel 2: attention edges via MFMA ----------------
// Tile: 64 edge rows x 128 cols. 512 threads = 8 waves, wave w owns head w (cols w*16..w*16+15).
// Phase 1: pe = (Eh+El) @ We (A-side hi/lo split == baseline f32-act x bf16-W profile),
//          score = K[src]*Q[dst]*0.25 + pe, per-head row sum via 16-lane butterfly,
//          exp(clip) -> z/wV atomics; score -> LDS hi/lo.
// Phase 2: ef = e + Oe_b + (Sh+Sl) @ Oe_w -> out_e + BN-e stats.
__global__ __launch_bounds__(512) void k_attn(const float* __restrict__ e,
    const int* __restrict__ src, const int* __restrict__ dst,
    const float* __restrict__ We, const float* __restrict__ Oe_w, const float* __restrict__ Oe_b,
    const float* __restrict__ qkvqe, float* __restrict__ wV, float* __restrict__ z,
    float* __restrict__ stats, float* __restrict__ out_e)
{
    __shared__ __align__(16) u16 eH[64 * S1];
    __shared__ __align__(16) u16 eL[64 * S1];
    __shared__ __align__(16) u16 scH[64 * S1];
    __shared__ __align__(16) u16 scL[64 * S1];
    __shared__ int drowS[64], srowS[64];

    const int t = threadIdx.x;
    const int lane = t & 63;
    const int wid = t >> 6;          // wave id == head id (N-tile)
    const int lrow = lane & 15;      // A-row within M-tile / D-col within head
    const int lgrp = lane >> 4;      // 0..3
    const int c = wid * 16 + lrow;   // this lane's output channel

    // ---- per-wave B fragments (We, Oe_w) in VGPRs, once ----
    short8 we8[4], oe8[4];
#pragma unroll
    for (int ks = 0; ks < 4; ++ks) {
        short8 a, b;
#pragma unroll
        for (int j = 0; j < 8; ++j) {
            int k = ks * 32 + lgrp * 8 + j;
            int idx = k * 128 + c;
            a[j] = (short)f2b(We[idx]);
            b[j] = (short)f2b(Oe_w[idx]);
        }
        we8[ks] = a; oe8[ks] = b;
    }
    const float oeb = Oe_b[c];
    float s1 = 0.f, s2 = 0.f;

    const int nTiles = ER / 64;  // 5000
    for (int tl = blockIdx.x; tl < nTiles; tl += gridDim.x) {
        const int rbase = tl * 64;
        // ---- stage e tile hi/lo + src/dst rows ----
        {
            int r = t >> 3, c0 = (t & 7) * 16;
            int re = rbase + r, ei = re >> 2, p = re & 3;
            if ((t & 7) == 0) { drowS[r] = dst[ei] * 4 + p; srowS[r] = src[ei] * 4 + p; }
            const float4* ee4 = (const float4*)(e + (size_t)re * 128 + c0);
            u32* EH = (u32*)(eH + r * S1 + c0);
            u32* EL = (u32*)(eL + r * S1 + c0);
#pragma unroll
            for (int q2 = 0; q2 < 4; ++q2) {
                float4 ev = ee4[q2];
                u16 e0 = f2b(ev.x), e1 = f2b(ev.y), e2 = f2b(ev.z), e3 = f2b(ev.w);
                EH[q2 * 2]     = (u32)e0 | ((u32)e1 << 16);
                EH[q2 * 2 + 1] = (u32)e2 | ((u32)e3 << 16);
                u16 g0 = f2b(ev.x - b2f(e0)), g1 = f2b(ev.y - b2f(e1));
                u16 g2 = f2b(ev.z - b2f(e2)), g3 = f2b(ev.w - b2f(e3));
                EL[q2 * 2]     = (u32)g0 | ((u32)g1 << 16);
                EL[q2 * 2 + 1] = (u32)g2 | ((u32)g3 << 16);
            }
        }
        __syncthreads();

        // ---- phase 1: pe MFMA + score epilogue ----
#pragma unroll
        for (int mt = 0; mt < 4; ++mt) {
            f32x4 ap = {0.f, 0.f, 0.f, 0.f};
#pragma unroll
            for (int ks = 0; ks < 4; ++ks) {
                const int off = (mt * 16 + lrow) * S1 + ks * 32 + lgrp * 8;
                short8 Eh = *(const short8*)(eH + off);
                short8 El = *(const short8*)(eL + off);
                ap = mfma16(Eh, we8[ks], ap);
                ap = mfma16(El, we8[ks], ap);
            }
#pragma unroll
            for (int q = 0; q < 4; ++q) {
                int rr = mt * 16 + lgrp * 4 + q;
                int dr = drowS[rr], sr = srowS[rr];
                float kq = qkvqe[(size_t)sr * 512 + 128 + c] * qkvqe[(size_t)dr * 512 + c] * 0.25f;
                float scv = kq + ap[q];
                float hs = scv;
                hs += __shfl_xor(hs, 1); hs += __shfl_xor(hs, 2);
                hs += __shfl_xor(hs, 4); hs += __shfl_xor(hs, 8);
                hs = fminf(fmaxf(hs, -5.f), 5.f);
                float sv = expf(hs);
                if (lrow == 0) atomicAdd(&z[dr * 8 + wid], sv);
                atomicAdd(&wV[(size_t)dr * 128 + c], qkvqe[(size_t)sr * 512 + 256 + c] * sv);
                u16 shh = f2b(scv);
                scH[rr * S1 + c] = shh;
                scL[rr * S1 + c] = f2b(scv - b2f(shh));
            }
        }
        __syncthreads();

        // ---- phase 2: ef = e + Oe_b + sc @ Oe_w ----
#pragma unroll
        for (int mt = 0; mt < 4; ++mt) {
            f32x4 ao = {0.f, 0.f, 0.f, 0.f};
#pragma unroll
            for (int ks = 0; ks < 4; ++ks) {
                const int off = (mt * 16 + lrow) * S1 + ks * 32 + lgrp * 8;
                short8 Sh = *(const short8*)(scH + off);
                short8 Sl = *(const short8*)(scL + off);
                ao = mfma16(Sh, oe8[ks], ao);
                ao = mfma16(Sl, oe8[ks], ao);
            }
#pragma unroll
            for (int q = 0; q < 4; ++q) {
                int rr = mt * 16 + lgrp * 4 + q;
                int re = rbase + rr;
                int off2 = rr * S1 + c;
                float ev = b2f(eH[off2]) + b2f(eL[off2]);
                float ef = ev + oeb + ao[q];
                out_e[(size_t)re * 128 + c] = ef;
                s1 += ef; s2 += ef * ef;
            }
        }
        __syncthreads();
    }
    atomicAdd(&stats[256 + c], s1);
    atomicAdd(&stats[384 + c], s2);
}

// ---------------- kernel 3: enhance edges via MFMA ----------------
__global__ __launch_bounds__(512) void k_enh(const float* __restrict__ h, const float* __restrict__ e,
    const int* __restrict__ src, const int* __restrict__ dst,
    const float* __restrict__ eWk, const float* __restrict__ eWv, const float* __restrict__ eWre,
    const float* __restrict__ qkvqe, float* __restrict__ henh)
{
    __shared__ __align__(16) u16 diffH[64 * S1];
    __shared__ __align__(16) u16 diffL[64 * S1];
    __shared__ __align__(16) u16 erH[64 * S1];
    __shared__ __align__(16) u16 erL[64 * S1];
    __shared__ int drowS[64];

    const int t = threadIdx.x;
    const int lane = t & 63;
    const int wid = t >> 6;          // wave id == head id (N-tile)
    const int lrow = lane & 15;      // A-row within M-tile / D-col within head
    const int lgrp = lane >> 4;      // 0..3

    // ---- load per-wave B fragments (weights) into VGPRs, once ----
    short8 wkh[4], wkl[4], wv8[4], wre8[4];
#pragma unroll
    for (int ks = 0; ks < 4; ++ks) {
        short8 a, b, c2, d2;
#pragma unroll
        for (int j = 0; j < 8; ++j) {
            int k = ks * 32 + lgrp * 8 + j;
            int idx = k * 128 + wid * 16 + lrow;
            float wk = eWk[idx];
            u16 hh = f2b(wk);
            a[j]  = (short)hh;
            b[j]  = (short)f2b(wk - b2f(hh));
            c2[j] = (short)f2b(eWv[idx]);
            d2[j] = (short)f2b(eWre[idx]);
        }
        wkh[ks] = a; wkl[ks] = b; wv8[ks] = c2; wre8[ks] = d2;
    }

    const int nTiles = ER / 64;  // 5000
    for (int tl = blockIdx.x; tl < nTiles; tl += gridDim.x) {
        const int rbase = tl * 64;
        // ---- stage tile: diff = relu(h[src]-h[dst]) and e rows, hi/lo bf16 ----
        {
            int r = t >> 3, c0 = (t & 7) * 16;
            int re = rbase + r, ei = re >> 2, p = re & 3;
            int sr = src[ei] * 4 + p, dr = dst[ei] * 4 + p;
            if ((t & 7) == 0) drowS[r] = dr;
            const float4* hs4 = (const float4*)(h + (size_t)sr * 128 + c0);
            const float4* hd4 = (const float4*)(h + (size_t)dr * 128 + c0);
            const float4* ee4 = (const float4*)(e + (size_t)re * 128 + c0);
            u32* dH = (u32*)(diffH + r * S1 + c0);
            u32* dL = (u32*)(diffL + r * S1 + c0);
            u32* eH = (u32*)(erH + r * S1 + c0);
            u32* eL = (u32*)(erL + r * S1 + c0);
#pragma unroll
            for (int q2 = 0; q2 < 4; ++q2) {
                float4 a = hs4[q2], b = hd4[q2], ev = ee4[q2];
                float d0 = fmaxf(a.x - b.x, 0.f), d1 = fmaxf(a.y - b.y, 0.f);
                float d2 = fmaxf(a.z - b.z, 0.f), d3 = fmaxf(a.w - b.w, 0.f);
                u16 h0 = f2b(d0), h1 = f2b(d1), h2 = f2b(d2), h3 = f2b(d3);
                dH[q2 * 2]     = (u32)h0 | ((u32)h1 << 16);
                dH[q2 * 2 + 1] = (u32)h2 | ((u32)h3 << 16);
                u16 l0 = f2b(d0 - b2f(h0)), l1 = f2b(d1 - b2f(h1));
                u16 l2 = f2b(d2 - b2f(h2)), l3 = f2b(d3 - b2f(h3));
                dL[q2 * 2]     = (u32)l0 | ((u32)l1 << 16);
                dL[q2 * 2 + 1] = (u32)l2 | ((u32)l3 << 16);
                u16 e0 = f2b(ev.x), e1 = f2b(ev.y), e2 = f2b(ev.z), e3 = f2b(ev.w);
                eH[q2 * 2]     = (u32)e0 | ((u32)e1 << 16);
                eH[q2 * 2 + 1] = (u32)e2 | ((u32)e3 << 16);
                u16 g0 = f2b(ev.x - b2f(e0)), g1 = f2b(ev.y - b2f(e1));
                u16 g2 = f2b(ev.z - b2f(e2)), g3 = f2b(ev.w - b2f(e3));
                eL[q2 * 2]     = (u32)g0 | ((u32)g1 << 16);
                eL[q2 * 2 + 1] = (u32)g2 | ((u32)g3 << 16);
            }
        }
        __syncthreads();

        // ---- MFMA + fused epilogue, per 16-row M-tile ----
#pragma unroll
        for (int mt = 0; mt < 4; ++mt) {
            f32x4 ak = {0.f, 0.f, 0.f, 0.f};
            f32x4 av = {0.f, 0.f, 0.f, 0.f};
            f32x4 ar = {0.f, 0.f, 0.f, 0.f};
#pragma unroll
            for (int ks = 0; ks < 4; ++ks) {
                const int off = (mt * 16 + lrow) * S1 + ks * 32 + lgrp * 8;
                short8 Ah = *(const short8*)(diffH + off);
                short8 Al = *(const short8*)(diffL + off);
                short8 Eh = *(const short8*)(erH + off);
                short8 El = *(const short8*)(erL + off);
                ak = mfma16(Ah, wkh[ks], ak);
                ak = mfma16(Al, wkh[ks], ak);
                ak = mfma16(Ah, wkl[ks], ak);
                av = mfma16(Ah, wv8[ks], av);
                av = mfma16(Al, wv8[ks], av);
                ar = mfma16(Eh, wre8[ks], ar);
                ar = mfma16(El, wre8[ks], ar);
            }
            // epilogue: norms (16-lane butterfly within head), score, msg, atomic max
#pragma unroll
            for (int q = 0; q < 4; ++q) {
                int rr = mt * 16 + lgrp * 4 + q;
                int dr = drowS[rr];
                float qd = qkvqe[(size_t)dr * 512 + 384 + wid * 16 + lrow];
                float kd = ak[q];
                float sk = kd * kd;
                sk += __shfl_xor(sk, 1); sk += __shfl_xor(sk, 2);
                sk += __shfl_xor(sk, 4); sk += __shfl_xor(sk, 8);
                float sq = qd * qd;
                sq += __shfl_xor(sq, 1); sq += __shfl_xor(sq, 2);
                sq += __shfl_xor(sq, 4); sq += __shfl_xor(sq, 8);
                float nk = sqrtf(sk + 1e-12f);
                float nq = sqrtf(sq + 1e-12f);
                float sc = qd * kd * (nk * nq + 1e-6f) + ar[q];
                float msg = sc * av[q];
                atomicMaxF(&henh[(size_t)dr * 128 + wid * 16 + lrow], msg);
            }
        }
        __syncthreads();
    }
}

// ---------------- kernel 4: combine h_attn + h_enh, Oh projection, residual, BN-h stats ----------------
__global__ __launch_bounds__(256) void k_comb(const float* __restrict__ h,
    const float* __restrict__ Oh_w, const float* __restrict__ Oh_b,
    const float* __restrict__ wV, const float* __restrict__ z, const float* __restrict__ henh,
    float* __restrict__ hf, float* __restrict__ stats)
{
    __shared__ __align__(16) u16 WT[128 * S1];
    __shared__ float xs[2][128];
    const int t = threadIdx.x;
    {
        int col = t & 127, half = t >> 7;
        for (int k = half * 64; k < half * 64 + 64; ++k) WT[col * S1 + k] = f2b(Oh_w[k * 128 + col]);
    }
    __syncthreads();
    const int rs = t >> 7, c = t & 127;
    const float ohb = Oh_b[c];
    float s1 = 0.f, s2 = 0.f;
    for (int base = blockIdx.x * 2; base < NR; base += gridDim.x * 2) {
        int r = base + rs;
        float hv = henh[r * 128 + c];
        u32 hb = __float_as_uint(hv);
        if (((hb >> 23) & 0xffu) == 0xffu) hv = 0.f;   // -inf/NaN (no in-edges) -> 0
        xs[rs][c] = wV[r * 128 + c] / (z[r * 8 + (c >> 4)] + 1e-6f) + hv;
        __syncthreads();
        float val = h[r * 128 + c] + ohb + mv128(&WT[c * S1], xs[rs]);
        hf[r * 128 + c] = val;
        s1 += val; s2 += val * val;
        __syncthreads();
    }
    atomicAdd(&stats[c], s1);
    atomicAdd(&stats[128 + c], s2);
}

// ---------------- kernel 5: BN scale/shift prep ----------------
__global__ void k_bnprep(const float* __restrict__ stats,
    const float* __restrict__ gh, const float* __restrict__ bh,
    const float* __restrict__ ge, const float* __restrict__ be, float* __restrict__ bnsc)
{
    int c = threadIdx.x;
    if (c < 128) {
        float m = stats[c] / (float)NR;
        float v = stats[128 + c] / (float)NR - m * m;
        float sc = gh[c] * rsqrtf(v + 1e-5f);
        bnsc[c] = sc; bnsc[128 + c] = bh[c] - m * sc;
        m = stats[256 + c] / (float)ER;
        v = stats[384 + c] / (float)ER - m * m;
        sc = ge[c] * rsqrtf(v + 1e-5f);
        bnsc[256 + c] = sc; bnsc[384 + c] = be[c] - m * sc;
    }
}

// ---------------- kernel 6: BN-h apply + FFN + residual -> out_h (f32) ----------------
__global__ __launch_bounds__(256) void k_ffn(const float* __restrict__ hf,
    const float* __restrict__ W1, const float* __restrict__ b1,
    const float* __restrict__ W2, const float* __restrict__ b2,
    const float* __restrict__ bnsc, float* __restrict__ out_h)
{
    __shared__ __align__(16) u16 W1T[256 * S1];
    __shared__ __align__(16) u16 W2T[128 * (2 * S1)];
    __shared__ float xn[128];
    __shared__ float tt[256];
    __shared__ float scs[128], shs[128];
    const int t = threadIdx.x;
    {
        for (int k = 0; k < 128; ++k) W1T[t * S1 + k] = f2b(W1[k * 256 + t]);
        int col = t & 127, half = t >> 7;
        for (int kk = 0; kk < 128; ++kk) { int k = half * 128 + kk; W2T[col * (2 * S1) + k] = f2b(W2[k * 128 + col]); }
        if (t < 128) { scs[t] = bnsc[t]; shs[t] = bnsc[128 + t]; }
    }
    __syncthreads();
    const float bb1 = b1[t];
    const float bb2 = (t < 128) ? b2[t] : 0.f;
    for (int r = blockIdx.x; r < NR; r += gridDim.x) {
        if (t < 128) xn[t] = hf[r * 128 + t] * scs[t] + shs[t];
        __syncthreads();
        tt[t] = fmaxf(bb1 + mv128(&W1T[t * S1], xn), 0.f);
        __syncthreads();
        if (t < 128) {
            float o = xn[t] + bb2 + mv256(&W2T[t * (2 * S1)], tt);
            out_h[r * 128 + t] = o;
        }
        __syncthreads();
    }
}

// ---------------- kernel 7: BN-e apply in place on d_out e-region (f32, float4) ----------------
__global__ __launch_bounds__(256) void k_bne(float* __restrict__ out_e, const float* __restrict__ bnsc)
{
    __shared__ float scs[128], shs[128];
    const int t = threadIdx.x;
    if (t < 128) { scs[t] = bnsc[256 + t]; shs[t] = bnsc[384 + t]; }
    __syncthreads();
    int idx = blockIdx.x * 256 + t;                // one float4 per thread
    const int total = ER * 128 / 4;                // 10,240,000
    for (; idx < total; idx += gridDim.x * 256) {
        float4 v = ((const float4*)out_e)[idx];
        int c0 = (idx * 4) & 127;
        v.x = v.x * scs[c0 + 0] + shs[c0 + 0];
        v.y = v.y * scs[c0 + 1] + shs[c0 + 1];
        v.z = v.z * scs[c0 + 2] + shs[c0 + 2];
        v.w = v.w * scs[c0 + 3] + shs[c0 + 3];
        ((float4*)out_e)[idx] = v;
    }
}

extern "C" void kernel_launch(void* const* d_in, const int* in_sizes, int n_in,
                              void* d_out, int out_size, void* d_ws, size_t ws_size,
                              hipStream_t stream)
{
    const float* h    = (const float*)d_in[0];
    const float* e    = (const float*)d_in[1];
    const int* src    = (const int*)d_in[2];
    const int* dst    = (const int*)d_in[3];
    const float* Wq   = (const float*)d_in[4];
    const float* Wk   = (const float*)d_in[5];
    const float* Wv   = (const float*)d_in[6];
    const float* We   = (const float*)d_in[7];
    const float* eWq  = (const float*)d_in[8];
    const float* eWk  = (const float*)d_in[9];
    const float* eWv  = (const float*)d_in[10];
    const float* eWre = (const float*)d_in[11];
    const float* Oh_w = (const float*)d_in[12];
    const float* Oh_b = (const float*)d_in[13];
    const float* Oe_w = (const float*)d_in[14];
    const float* Oe_b = (const float*)d_in[15];
    const float* bnhg = (const float*)d_in[16];
    const float* bnhb = (const float*)d_in[17];
    const float* bneg = (const float*)d_in[18];
    const float* bneb = (const float*)d_in[19];
    const float* W1   = (const float*)d_in[20];
    const float* b1   = (const float*)d_in[21];
    const float* W2   = (const float*)d_in[22];
    const float* b2   = (const float*)d_in[23];

    float* out_h = (float*)d_out;
    float* out_e = out_h + (size_t)NR * 128;

    char* w = (char*)d_ws;
    float* qkvqe = (float*)(w);                         // NR*512 f32  = 81,920,000 B
    float* wV    = (float*)(w + 81920000);              // NR*128 f32  = 20,480,000 B
    float* z     = (float*)(w + 102400000);             // NR*8  f32   =  1,280,000 B
    float* henh  = (float*)(w + 103680000);             // NR*128 f32  = 20,480,000 B
    float* hf    = (float*)(w + 124160000);             // NR*128 f32  = 20,480,000 B
    float* stats = (float*)(w + 144640000);             // 512 f32
    float* bnsc  = (float*)(w + 144642048);             // 512 f32

    hipMemsetAsync(wV,    0,    20480000, stream);
    hipMemsetAsync(z,     0,    1280000,  stream);
    hipMemsetAsync(stats, 0,    2048,     stream);
    hipMemsetAsync(henh,  0xFF, 20480000, stream);      // -NaN: identity for atomicMaxF, filtered by finite check

    k_qkvqe<<<256, 512, 0, stream>>>(h, Wq, Wk, Wv, eWq, qkvqe);
    k_attn <<<1024, 512, 0, stream>>>(e, src, dst, We, Oe_w, Oe_b, qkvqe, wV, z, stats, out_e);
    k_enh  <<<1024, 512, 0, stream>>>(h, e, src, dst, eWk, eWv, eWre, qkvqe, henh);
    k_comb <<<1024, 256, 0, stream>>>(h, Oh_w, Oh_b, wV, z, henh, hf, stats);
    k_bnprep<<<1, 128, 0, stream>>>(stats, bnhg, bnhb, bneg, bneb, bnsc);
    k_ffn  <<<256, 256, 0, stream>>>(hf, W1, b1, W2, b2, bnsc, out_h);
    k_bne  <<<40000, 256, 0, stream>>>(out_e, bnsc);
}

// Round 3
// 1941.875 us; speedup vs baseline: 2.1869x; 1.0572x over previous
//
#include <hip/hip_runtime.h>
#include <hip/hip_bf16.h>

#define NN 10000
#define NE 80000
#define PP 4
#define CC 128
#define NR (NN*PP)   // 40000 node rows
#define ER (NE*PP)   // 320000 edge rows
#define S1 136       // LDS row stride (u16) for bf16 K=128 rows: 68 dwords == 4 mod 32; 17 quads -> conflict-free b128

typedef unsigned short u16;
typedef unsigned int   u32;
typedef __attribute__((ext_vector_type(8))) short short8;   // 8 bf16 (4 VGPRs) MFMA A/B frag
typedef __attribute__((ext_vector_type(4))) float f32x4;    // MFMA C/D frag

__device__ inline float b2f(u16 v) { return __uint_as_float(((u32)v) << 16); }
__device__ inline float bfl(u32 u) { return __uint_as_float(u << 16); }
__device__ inline float bfh(u32 u) { return __uint_as_float(u & 0xffff0000u); }
__device__ inline u16 f2b(float f) {
    u32 x = __float_as_uint(f);
    return (u16)((x + 0x7fffu + ((x >> 16) & 1u)) >> 16);
}
__device__ inline void atomicMaxF(float* addr, float val) {
    if (val >= 0.f) atomicMax((int*)addr, __float_as_int(val));
    else            atomicMin((u32*)addr, __float_as_uint(val));
}
__device__ inline f32x4 mfma16(short8 a, short8 b, f32x4 c) {
    return __builtin_amdgcn_mfma_f32_16x16x32_bf16(a, b, c, 0, 0, 0);
}

// acc = sum_k x[k] * WTrow[k], K=128, bf16 weight row in LDS
__device__ inline float mv128(const u16* WTrow, const float* x) {
    const uint4* w4 = (const uint4*)WTrow;
    float acc = 0.f;
#pragma unroll
    for (int j = 0; j < 16; ++j) {
        uint4 w = w4[j];
        const float* p = x + 8 * j;
        acc += p[0]*bfl(w.x) + p[1]*bfh(w.x) + p[2]*bfl(w.y) + p[3]*bfh(w.y)
             + p[4]*bfl(w.z) + p[5]*bfh(w.z) + p[6]*bfl(w.w) + p[7]*bfh(w.w);
    }
    return acc;
}
__device__ inline float mv256(const u16* WTrow, const float* x) {
    const uint4* w4 = (const uint4*)WTrow;
    float acc = 0.f;
#pragma unroll
    for (int j = 0; j < 32; ++j) {
        uint4 w = w4[j];
        const float* p = x + 8 * j;
        acc += p[0]*bfl(w.x) + p[1]*bfh(w.x) + p[2]*bfl(w.y) + p[3]*bfh(w.y)
             + p[4]*bfl(w.z) + p[5]*bfh(w.z) + p[6]*bfl(w.w) + p[7]*bfh(w.w);
    }
    return acc;
}

// ---------------- kernel 1: [Q|K|V|Qe] = h @ [Wq|Wk|Wv|eWq] via MFMA, f32 out ----------------
// Tile: 64 node rows x 512 cols. 8 waves; wave w owns cols w*64..w*64+63 (4 N-subtiles of 16).
__global__ __launch_bounds__(512) void k_qkvqe(const float* __restrict__ h,
    const float* __restrict__ Wq, const float* __restrict__ Wk,
    const float* __restrict__ Wv, const float* __restrict__ eWq,
    float* __restrict__ out)
{
    __shared__ __align__(16) u16 hH[64 * S1];
    __shared__ __align__(16) u16 hL[64 * S1];
    const int t = threadIdx.x;
    const int lane = t & 63;
    const int wid = t >> 6;
    const int lrow = lane & 15;
    const int lgrp = lane >> 4;

    // per-wave B fragments for its 64 output cols: wf[nt][ks]
    short8 wf[4][4];
#pragma unroll
    for (int nt = 0; nt < 4; ++nt) {
        int col = wid * 64 + nt * 16 + lrow;
        int sel = col >> 7, wc = col & 127;
        const float* W = (sel == 0) ? Wq : (sel == 1) ? Wk : (sel == 2) ? Wv : eWq;
#pragma unroll
        for (int ks = 0; ks < 4; ++ks) {
            short8 a;
#pragma unroll
            for (int j = 0; j < 8; ++j) {
                int k = ks * 32 + lgrp * 8 + j;
                a[j] = (short)f2b(W[k * 128 + wc]);
            }
            wf[nt][ks] = a;
        }
    }

    const int nTiles = NR / 64;  // 625
    for (int tl = blockIdx.x; tl < nTiles; tl += gridDim.x) {
        const int rbase = tl * 64;
        {
            int r = t >> 3, c0 = (t & 7) * 16;
            const float4* h4 = (const float4*)(h + (size_t)(rbase + r) * 128 + c0);
            u32* HH = (u32*)(hH + r * S1 + c0);
            u32* HL = (u32*)(hL + r * S1 + c0);
#pragma unroll
            for (int q2 = 0; q2 < 4; ++q2) {
                float4 v = h4[q2];
                u16 h0 = f2b(v.x), h1 = f2b(v.y), h2 = f2b(v.z), h3 = f2b(v.w);
                HH[q2 * 2]     = (u32)h0 | ((u32)h1 << 16);
                HH[q2 * 2 + 1] = (u32)h2 | ((u32)h3 << 16);
                u16 l0 = f2b(v.x - b2f(h0)), l1 = f2b(v.y - b2f(h1));
                u16 l2 = f2b(v.z - b2f(h2)), l3 = f2b(v.w - b2f(h3));
                HL[q2 * 2]     = (u32)l0 | ((u32)l1 << 16);
                HL[q2 * 2 + 1] = (u32)l2 | ((u32)l3 << 16);
            }
        }
        __syncthreads();
#pragma unroll
        for (int mt = 0; mt < 4; ++mt) {
            short8 Hh[4], Hl[4];
#pragma unroll
            for (int ks = 0; ks < 4; ++ks) {
                const int off = (mt * 16 + lrow) * S1 + ks * 32 + lgrp * 8;
                Hh[ks] = *(const short8*)(hH + off);
                Hl[ks] = *(const short8*)(hL + off);
            }
#pragma unroll
            for (int nt = 0; nt < 4; ++nt) {
                f32x4 acc = {0.f, 0.f, 0.f, 0.f};
#pragma unroll
                for (int ks = 0; ks < 4; ++ks) {
                    acc = mfma16(Hh[ks], wf[nt][ks], acc);
                    acc = mfma16(Hl[ks], wf[nt][ks], acc);
                }
#pragma unroll
                for (int q = 0; q < 4; ++q) {
                    int r = rbase + mt * 16 + lgrp * 4 + q;
                    out[(size_t)r * 512 + wid * 64 + nt * 16 + lrow] = acc[q];
                }
            }
        }
        __syncthreads();
    }
}

// ---------------- kernel 2: attention edges via MFMA, LDS-halved (score reuses e-tile) ------
// Phase 1: MFMA pe over all 4 M-tiles into regs -> barrier -> epilogue (score, exp, atomics)
// writes scores into the SAME LDS buffers -> barrier -> phase 2 MFMA sc @ Oe_w; residual e
// re-read from global (L2-hot).
__global__ __launch_bounds__(512, 8) void k_attn(const float* __restrict__ e,
    const int* __restrict__ src, const int* __restrict__ dst,
    const float* __restrict__ We, const float* __restrict__ Oe_w, const float* __restrict__ Oe_b,
    const float* __restrict__ qkvqe, float* __restrict__ wV, float* __restrict__ z,
    float* __restrict__ stats, float* __restrict__ out_e)
{
    __shared__ __align__(16) u16 eH[64 * S1];   // e hi  -> reused as score hi
    __shared__ __align__(16) u16 eL[64 * S1];   // e lo  -> reused as score lo
    __shared__ int drowS[64], srowS[64];

    const int t = threadIdx.x;
    const int lane = t & 63;
    const int wid = t >> 6;          // wave id == head id (N-tile)
    const int lrow = lane & 15;
    const int lgrp = lane >> 4;
    const int c = wid * 16 + lrow;   // this lane's output channel

    short8 we8[4], oe8[4];
#pragma unroll
    for (int ks = 0; ks < 4; ++ks) {
        short8 a, b;
#pragma unroll
        for (int j = 0; j < 8; ++j) {
            int k = ks * 32 + lgrp * 8 + j;
            int idx = k * 128 + c;
            a[j] = (short)f2b(We[idx]);
            b[j] = (short)f2b(Oe_w[idx]);
        }
        we8[ks] = a; oe8[ks] = b;
    }
    const float oeb = Oe_b[c];
    float s1 = 0.f, s2 = 0.f;

    const int nTiles = ER / 64;  // 5000
    for (int tl = blockIdx.x; tl < nTiles; tl += gridDim.x) {
        const int rbase = tl * 64;
        {
            int r = t >> 3, c0 = (t & 7) * 16;
            int re = rbase + r, ei = re >> 2, p = re & 3;
            if ((t & 7) == 0) { drowS[r] = dst[ei] * 4 + p; srowS[r] = src[ei] * 4 + p; }
            const float4* ee4 = (const float4*)(e + (size_t)re * 128 + c0);
            u32* EH = (u32*)(eH + r * S1 + c0);
            u32* EL = (u32*)(eL + r * S1 + c0);
#pragma unroll
            for (int q2 = 0; q2 < 4; ++q2) {
                float4 ev = ee4[q2];
                u16 e0 = f2b(ev.x), e1 = f2b(ev.y), e2 = f2b(ev.z), e3 = f2b(ev.w);
                EH[q2 * 2]     = (u32)e0 | ((u32)e1 << 16);
                EH[q2 * 2 + 1] = (u32)e2 | ((u32)e3 << 16);
                u16 g0 = f2b(ev.x - b2f(e0)), g1 = f2b(ev.y - b2f(e1));
                u16 g2 = f2b(ev.z - b2f(e2)), g3 = f2b(ev.w - b2f(e3));
                EL[q2 * 2]     = (u32)g0 | ((u32)g1 << 16);
                EL[q2 * 2 + 1] = (u32)g2 | ((u32)g3 << 16);
            }
        }
        __syncthreads();

        // ---- phase 1 MFMA: pe for all 4 M-tiles into registers ----
        f32x4 ap0 = {0.f,0.f,0.f,0.f}, ap1 = {0.f,0.f,0.f,0.f};
        f32x4 ap2 = {0.f,0.f,0.f,0.f}, ap3 = {0.f,0.f,0.f,0.f};
#pragma unroll
        for (int ks = 0; ks < 4; ++ks) {
            const int boff = ks * 32 + lgrp * 8;
            ap0 = mfma16(*(const short8*)(eH + (0 * 16 + lrow) * S1 + boff), we8[ks], ap0);
            ap0 = mfma16(*(const short8*)(eL + (0 * 16 + lrow) * S1 + boff), we8[ks], ap0);
            ap1 = mfma16(*(const short8*)(eH + (1 * 16 + lrow) * S1 + boff), we8[ks], ap1);
            ap1 = mfma16(*(const short8*)(eL + (1 * 16 + lrow) * S1 + boff), we8[ks], ap1);
            ap2 = mfma16(*(const short8*)(eH + (2 * 16 + lrow) * S1 + boff), we8[ks], ap2);
            ap2 = mfma16(*(const short8*)(eL + (2 * 16 + lrow) * S1 + boff), we8[ks], ap2);
            ap3 = mfma16(*(const short8*)(eH + (3 * 16 + lrow) * S1 + boff), we8[ks], ap3);
            ap3 = mfma16(*(const short8*)(eL + (3 * 16 + lrow) * S1 + boff), we8[ks], ap3);
        }
        __syncthreads();   // all e-tile reads done; buffers may be overwritten

        // ---- epilogue 1: score, exp, atomics; scores -> eH/eL ----
#pragma unroll
        for (int mt = 0; mt < 4; ++mt) {
            f32x4 ap = (mt == 0) ? ap0 : (mt == 1) ? ap1 : (mt == 2) ? ap2 : ap3;
#pragma unroll
            for (int q = 0; q < 4; ++q) {
                int rr = mt * 16 + lgrp * 4 + q;
                int dr = drowS[rr], sr = srowS[rr];
                float kq = qkvqe[(size_t)sr * 512 + 128 + c] * qkvqe[(size_t)dr * 512 + c] * 0.25f;
                float scv = kq + ap[q];
                float hs = scv;
                hs += __shfl_xor(hs, 1); hs += __shfl_xor(hs, 2);
                hs += __shfl_xor(hs, 4); hs += __shfl_xor(hs, 8);
                hs = fminf(fmaxf(hs, -5.f), 5.f);
                float sv = expf(hs);
                if (lrow == 0) atomicAdd(&z[dr * 8 + wid], sv);
                atomicAdd(&wV[(size_t)dr * 128 + c], qkvqe[(size_t)sr * 512 + 256 + c] * sv);
                u16 shh = f2b(scv);
                eH[rr * S1 + c] = shh;
                eL[rr * S1 + c] = f2b(scv - b2f(shh));
            }
        }
        __syncthreads();

        // ---- phase 2: ef = e + Oe_b + sc @ Oe_w ----
#pragma unroll
        for (int mt = 0; mt < 4; ++mt) {
            f32x4 ao = {0.f, 0.f, 0.f, 0.f};
#pragma unroll
            for (int ks = 0; ks < 4; ++ks) {
                const int off = (mt * 16 + lrow) * S1 + ks * 32 + lgrp * 8;
                ao = mfma16(*(const short8*)(eH + off), oe8[ks], ao);
                ao = mfma16(*(const short8*)(eL + off), oe8[ks], ao);
            }
#pragma unroll
            for (int q = 0; q < 4; ++q) {
                int rr = mt * 16 + lgrp * 4 + q;
                int re = rbase + rr;
                float ev = e[(size_t)re * 128 + c];   // L2-hot re-read (residual)
                float ef = ev + oeb + ao[q];
                out_e[(size_t)re * 128 + c] = ef;
                s1 += ef; s2 += ef * ef;
            }
        }
        __syncthreads();   // protect score buffers until next stage
    }
    atomicAdd(&stats[256 + c], s1);
    atomicAdd(&stats[384 + c], s2);
}

// ---------------- kernel 3: enhance edges via MFMA ----------------
__global__ __launch_bounds__(512) void k_enh(const float* __restrict__ h, const float* __restrict__ e,
    const int* __restrict__ src, const int* __restrict__ dst,
    const float* __restrict__ eWk, const float* __restrict__ eWv, const float* __restrict__ eWre,
    const float* __restrict__ qkvqe, float* __restrict__ henh)
{
    __shared__ __align__(16) u16 diffH[64 * S1];
    __shared__ __align__(16) u16 diffL[64 * S1];
    __shared__ __align__(16) u16 erH[64 * S1];
    __shared__ __align__(16) u16 erL[64 * S1];
    __shared__ int drowS[64];

    const int t = threadIdx.x;
    const int lane = t & 63;
    const int wid = t >> 6;          // wave id == head id (N-tile)
    const int lrow = lane & 15;      // A-row within M-tile / D-col within head
    const int lgrp = lane >> 4;      // 0..3

    // ---- load per-wave B fragments (weights) into VGPRs, once ----
    short8 wkh[4], wkl[4], wv8[4], wre8[4];
#pragma unroll
    for (int ks = 0; ks < 4; ++ks) {
        short8 a, b, c2, d2;
#pragma unroll
        for (int j = 0; j < 8; ++j) {
            int k = ks * 32 + lgrp * 8 + j;
            int idx = k * 128 + wid * 16 + lrow;
            float wk = eWk[idx];
            u16 hh = f2b(wk);
            a[j]  = (short)hh;
            b[j]  = (short)f2b(wk - b2f(hh));
            c2[j] = (short)f2b(eWv[idx]);
            d2[j] = (short)f2b(eWre[idx]);
        }
        wkh[ks] = a; wkl[ks] = b; wv8[ks] = c2; wre8[ks] = d2;
    }

    const int nTiles = ER / 64;  // 5000
    for (int tl = blockIdx.x; tl < nTiles; tl += gridDim.x) {
        const int rbase = tl * 64;
        // ---- stage tile: diff = relu(h[src]-h[dst]) and e rows, hi/lo bf16 ----
        {
            int r = t >> 3, c0 = (t & 7) * 16;
            int re = rbase + r, ei = re >> 2, p = re & 3;
            int sr = src[ei] * 4 + p, dr = dst[ei] * 4 + p;
            if ((t & 7) == 0) drowS[r] = dr;
            const float4* hs4 = (const float4*)(h + (size_t)sr * 128 + c0);
            const float4* hd4 = (const float4*)(h + (size_t)dr * 128 + c0);
            const float4* ee4 = (const float4*)(e + (size_t)re * 128 + c0);
            u32* dH = (u32*)(diffH + r * S1 + c0);
            u32* dL = (u32*)(diffL + r * S1 + c0);
            u32* eH = (u32*)(erH + r * S1 + c0);
            u32* eL = (u32*)(erL + r * S1 + c0);
#pragma unroll
            for (int q2 = 0; q2 < 4; ++q2) {
                float4 a = hs4[q2], b = hd4[q2], ev = ee4[q2];
                float d0 = fmaxf(a.x - b.x, 0.f), d1 = fmaxf(a.y - b.y, 0.f);
                float d2 = fmaxf(a.z - b.z, 0.f), d3 = fmaxf(a.w - b.w, 0.f);
                u16 h0 = f2b(d0), h1 = f2b(d1), h2 = f2b(d2), h3 = f2b(d3);
                dH[q2 * 2]     = (u32)h0 | ((u32)h1 << 16);
                dH[q2 * 2 + 1] = (u32)h2 | ((u32)h3 << 16);
                u16 l0 = f2b(d0 - b2f(h0)), l1 = f2b(d1 - b2f(h1));
                u16 l2 = f2b(d2 - b2f(h2)), l3 = f2b(d3 - b2f(h3));
                dL[q2 * 2]     = (u32)l0 | ((u32)l1 << 16);
                dL[q2 * 2 + 1] = (u32)l2 | ((u32)l3 << 16);
                u16 e0 = f2b(ev.x), e1 = f2b(ev.y), e2 = f2b(ev.z), e3 = f2b(ev.w);
                eH[q2 * 2]     = (u32)e0 | ((u32)e1 << 16);
                eH[q2 * 2 + 1] = (u32)e2 | ((u32)e3 << 16);
                u16 g0 = f2b(ev.x - b2f(e0)), g1 = f2b(ev.y - b2f(e1));
                u16 g2 = f2b(ev.z - b2f(e2)), g3 = f2b(ev.w - b2f(e3));
                eL[q2 * 2]     = (u32)g0 | ((u32)g1 << 16);
                eL[q2 * 2 + 1] = (u32)g2 | ((u32)g3 << 16);
            }
        }
        __syncthreads();

        // ---- MFMA + fused epilogue, per 16-row M-tile ----
#pragma unroll
        for (int mt = 0; mt < 4; ++mt) {
            f32x4 ak = {0.f, 0.f, 0.f, 0.f};
            f32x4 av = {0.f, 0.f, 0.f, 0.f};
            f32x4 ar = {0.f, 0.f, 0.f, 0.f};
#pragma unroll
            for (int ks = 0; ks < 4; ++ks) {
                const int off = (mt * 16 + lrow) * S1 + ks * 32 + lgrp * 8;
                short8 Ah = *(const short8*)(diffH + off);
                short8 Al = *(const short8*)(diffL + off);
                short8 Eh = *(const short8*)(erH + off);
                short8 El = *(const short8*)(erL + off);
                ak = mfma16(Ah, wkh[ks], ak);
                ak = mfma16(Al, wkh[ks], ak);
                ak = mfma16(Ah, wkl[ks], ak);
                av = mfma16(Ah, wv8[ks], av);
                av = mfma16(Al, wv8[ks], av);
                ar = mfma16(Eh, wre8[ks], ar);
                ar = mfma16(El, wre8[ks], ar);
            }
            // epilogue: norms (16-lane butterfly within head), score, msg, atomic max
#pragma unroll
            for (int q = 0; q < 4; ++q) {
                int rr = mt * 16 + lgrp * 4 + q;
                int dr = drowS[rr];
                float qd = qkvqe[(size_t)dr * 512 + 384 + wid * 16 + lrow];
                float kd = ak[q];
                float sk = kd * kd;
                sk += __shfl_xor(sk, 1); sk += __shfl_xor(sk, 2);
                sk += __shfl_xor(sk, 4); sk += __shfl_xor(sk, 8);
                float sq = qd * qd;
                sq += __shfl_xor(sq, 1); sq += __shfl_xor(sq, 2);
                sq += __shfl_xor(sq, 4); sq += __shfl_xor(sq, 8);
                float nk = sqrtf(sk + 1e-12f);
                float nq = sqrtf(sq + 1e-12f);
                float sc = qd * kd * (nk * nq + 1e-6f) + ar[q];
                float msg = sc * av[q];
                atomicMaxF(&henh[(size_t)dr * 128 + wid * 16 + lrow], msg);
            }
        }
        __syncthreads();
    }
}

// ---------------- kernel 4: combine h_attn + h_enh, Oh projection, residual, BN-h stats ----------------
__global__ __launch_bounds__(256) void k_comb(const float* __restrict__ h,
    const float* __restrict__ Oh_w, const float* __restrict__ Oh_b,
    const float* __restrict__ wV, const float* __restrict__ z, const float* __restrict__ henh,
    float* __restrict__ hf, float* __restrict__ stats)
{
    __shared__ __align__(16) u16 WT[128 * S1];
    __shared__ float xs[2][128];
    const int t = threadIdx.x;
    {
        int col = t & 127, half = t >> 7;
        for (int k = half * 64; k < half * 64 + 64; ++k) WT[col * S1 + k] = f2b(Oh_w[k * 128 + col]);
    }
    __syncthreads();
    const int rs = t >> 7, c = t & 127;
    const float ohb = Oh_b[c];
    float s1 = 0.f, s2 = 0.f;
    for (int base = blockIdx.x * 2; base < NR; base += gridDim.x * 2) {
        int r = base + rs;
        float hv = henh[r * 128 + c];
        u32 hb = __float_as_uint(hv);
        if (((hb >> 23) & 0xffu) == 0xffu) hv = 0.f;   // -inf/NaN (no in-edges) -> 0
        xs[rs][c] = wV[r * 128 + c] / (z[r * 8 + (c >> 4)] + 1e-6f) + hv;
        __syncthreads();
        float val = h[r * 128 + c] + ohb + mv128(&WT[c * S1], xs[rs]);
        hf[r * 128 + c] = val;
        s1 += val; s2 += val * val;
        __syncthreads();
    }
    atomicAdd(&stats[c], s1);
    atomicAdd(&stats[128 + c], s2);
}

// ---------------- kernel 5: BN scale/shift prep ----------------
__global__ void k_bnprep(const float* __restrict__ stats,
    const float* __restrict__ gh, const float* __restrict__ bh,
    const float* __restrict__ ge, const float* __restrict__ be, float* __restrict__ bnsc)
{
    int c = threadIdx.x;
    if (c < 128) {
        float m = stats[c] / (float)NR;
        float v = stats[128 + c] / (float)NR - m * m;
        float sc = gh[c] * rsqrtf(v + 1e-5f);
        bnsc[c] = sc; bnsc[128 + c] = bh[c] - m * sc;
        m = stats[256 + c] / (float)ER;
        v = stats[384 + c] / (float)ER - m * m;
        sc = ge[c] * rsqrtf(v + 1e-5f);
        bnsc[256 + c] = sc; bnsc[384 + c] = be[c] - m * sc;
    }
}

// ---------------- kernel 6: BN-h apply + FFN + residual -> out_h (f32) ----------------
__global__ __launch_bounds__(256) void k_ffn(const float* __restrict__ hf,
    const float* __restrict__ W1, const float* __restrict__ b1,
    const float* __restrict__ W2, const float* __restrict__ b2,
    const float* __restrict__ bnsc, float* __restrict__ out_h)
{
    __shared__ __align__(16) u16 W1T[256 * S1];
    __shared__ __align__(16) u16 W2T[128 * (2 * S1)];
    __shared__ float xn[128];
    __shared__ float tt[256];
    __shared__ float scs[128], shs[128];
    const int t = threadIdx.x;
    {
        for (int k = 0; k < 128; ++k) W1T[t * S1 + k] = f2b(W1[k * 256 + t]);
        int col = t & 127, half = t >> 7;
        for (int kk = 0; kk < 128; ++kk) { int k = half * 128 + kk; W2T[col * (2 * S1) + k] = f2b(W2[k * 128 + col]); }
        if (t < 128) { scs[t] = bnsc[t]; shs[t] = bnsc[128 + t]; }
    }
    __syncthreads();
    const float bb1 = b1[t];
    const float bb2 = (t < 128) ? b2[t] : 0.f;
    for (int r = blockIdx.x; r < NR; r += gridDim.x) {
        if (t < 128) xn[t] = hf[r * 128 + t] * scs[t] + shs[t];
        __syncthreads();
        tt[t] = fmaxf(bb1 + mv128(&W1T[t * S1], xn), 0.f);
        __syncthreads();
        if (t < 128) {
            float o = xn[t] + bb2 + mv256(&W2T[t * (2 * S1)], tt);
            out_h[r * 128 + t] = o;
        }
        __syncthreads();
    }
}

// ---------------- kernel 7: BN-e apply in place on d_out e-region (f32, float4) ----------------
__global__ __launch_bounds__(256) void k_bne(float* __restrict__ out_e, const float* __restrict__ bnsc)
{
    __shared__ float scs[128], shs[128];
    const int t = threadIdx.x;
    if (t < 128) { scs[t] = bnsc[256 + t]; shs[t] = bnsc[384 + t]; }
    __syncthreads();
    int idx = blockIdx.x * 256 + t;                // one float4 per thread
    const int total = ER * 128 / 4;                // 10,240,000
    for (; idx < total; idx += gridDim.x * 256) {
        float4 v = ((const float4*)out_e)[idx];
        int c0 = (idx * 4) & 127;
        v.x = v.x * scs[c0 + 0] + shs[c0 + 0];
        v.y = v.y * scs[c0 + 1] + shs[c0 + 1];
        v.z = v.z * scs[c0 + 2] + shs[c0 + 2];
        v.w = v.w * scs[c0 + 3] + shs[c0 + 3];
        ((float4*)out_e)[idx] = v;
    }
}

extern "C" void kernel_launch(void* const* d_in, const int* in_sizes, int n_in,
                              void* d_out, int out_size, void* d_ws, size_t ws_size,
                              hipStream_t stream)
{
    const float* h    = (const float*)d_in[0];
    const float* e    = (const float*)d_in[1];
    const int* src    = (const int*)d_in[2];
    const int* dst    = (const int*)d_in[3];
    const float* Wq   = (const float*)d_in[4];
    const float* Wk   = (const float*)d_in[5];
    const float* Wv   = (const float*)d_in[6];
    const float* We   = (const float*)d_in[7];
    const float* eWq  = (const float*)d_in[8];
    const float* eWk  = (const float*)d_in[9];
    const float* eWv  = (const float*)d_in[10];
    const float* eWre = (const float*)d_in[11];
    const float* Oh_w = (const float*)d_in[12];
    const float* Oh_b = (const float*)d_in[13];
    const float* Oe_w = (const float*)d_in[14];
    const float* Oe_b = (const float*)d_in[15];
    const float* bnhg = (const float*)d_in[16];
    const float* bnhb = (const float*)d_in[17];
    const float* bneg = (const float*)d_in[18];
    const float* bneb = (const float*)d_in[19];
    const float* W1   = (const float*)d_in[20];
    const float* b1   = (const float*)d_in[21];
    const float* W2   = (const float*)d_in[22];
    const float* b2   = (const float*)d_in[23];

    float* out_h = (float*)d_out;
    float* out_e = out_h + (size_t)NR * 128;

    char* w = (char*)d_ws;
    float* qkvqe = (float*)(w);                         // NR*512 f32  = 81,920,000 B
    float* wV    = (float*)(w + 81920000);              // NR*128 f32  = 20,480,000 B
    float* z     = (float*)(w + 102400000);             // NR*8  f32   =  1,280,000 B
    float* henh  = (float*)(w + 103680000);             // NR*128 f32  = 20,480,000 B
    float* hf    = (float*)(w + 124160000);             // NR*128 f32  = 20,480,000 B
    float* stats = (float*)(w + 144640000);             // 512 f32
    float* bnsc  = (float*)(w + 144642048);             // 512 f32

    hipMemsetAsync(wV,    0,    20480000, stream);
    hipMemsetAsync(z,     0,    1280000,  stream);
    hipMemsetAsync(stats, 0,    2048,     stream);
    hipMemsetAsync(henh,  0xFF, 20480000, stream);      // -NaN: identity for atomicMaxF, filtered by finite check

    k_qkvqe<<<625, 512, 0, stream>>>(h, Wq, Wk, Wv, eWq, qkvqe);
    k_attn <<<1024, 512, 0, stream>>>(e, src, dst, We, Oe_w, Oe_b, qkvqe, wV, z, stats, out_e);
    k_enh  <<<1024, 512, 0, stream>>>(h, e, src, dst, eWk, eWv, eWre, qkvqe, henh);
    k_comb <<<1024, 256, 0, stream>>>(h, Oh_w, Oh_b, wV, z, henh, hf, stats);
    k_bnprep<<<1, 128, 0, stream>>>(stats, bnhg, bnhb, bneg, bneb, bnsc);
    k_ffn  <<<256, 256, 0, stream>>>(hf, W1, b1, W2, b2, bnsc, out_h);
    k_bne  <<<40000, 256, 0, stream>>>(out_e, bnsc);
}

// Round 4
// 1581.507 us; speedup vs baseline: 2.6852x; 1.2279x over previous
//
#include <hip/hip_runtime.h>
#include <hip/hip_bf16.h>

#define NN 10000
#define NE 80000
#define PP 4
#define CC 128
#define NR (NN*PP)   // 40000 node rows
#define ER (NE*PP)   // 320000 edge rows
#define S1 136       // LDS row stride (u16) for bf16 K=128 rows: 68 dwords == 4 mod 32; 17 quads -> conflict-free b128
#define S2 264       // LDS row stride (u16) for K=256 rows: 132 dwords == 4 mod 32; 33 quads -> conflict-free b128

typedef unsigned short u16;
typedef unsigned int   u32;
typedef __attribute__((ext_vector_type(8))) short short8;   // 8 bf16 (4 VGPRs) MFMA A/B frag
typedef __attribute__((ext_vector_type(4))) float f32x4;    // MFMA C/D frag

__device__ inline float b2f(u16 v) { return __uint_as_float(((u32)v) << 16); }
__device__ inline u16 f2b(float f) {
    u32 x = __float_as_uint(f);
    return (u16)((x + 0x7fffu + ((x >> 16) & 1u)) >> 16);
}
__device__ inline void atomicMaxF(float* addr, float val) {
    if (val >= 0.f) atomicMax((int*)addr, __float_as_int(val));
    else            atomicMin((u32*)addr, __float_as_uint(val));
}
__device__ inline f32x4 mfma16(short8 a, short8 b, f32x4 c) {
    return __builtin_amdgcn_mfma_f32_16x16x32_bf16(a, b, c, 0, 0, 0);
}

// ---------------- kernel 1: [Q|K|V|Qe] = h @ [Wq|Wk|Wv|eWq] via MFMA, f32 out ----------------
__global__ __launch_bounds__(512) void k_qkvqe(const float* __restrict__ h,
    const float* __restrict__ Wq, const float* __restrict__ Wk,
    const float* __restrict__ Wv, const float* __restrict__ eWq,
    float* __restrict__ out)
{
    __shared__ __align__(16) u16 hH[64 * S1];
    __shared__ __align__(16) u16 hL[64 * S1];
    const int t = threadIdx.x;
    const int lane = t & 63;
    const int wid = t >> 6;
    const int lrow = lane & 15;
    const int lgrp = lane >> 4;

    short8 wf[4][4];
#pragma unroll
    for (int nt = 0; nt < 4; ++nt) {
        int col = wid * 64 + nt * 16 + lrow;
        int sel = col >> 7, wc = col & 127;
        const float* W = (sel == 0) ? Wq : (sel == 1) ? Wk : (sel == 2) ? Wv : eWq;
#pragma unroll
        for (int ks = 0; ks < 4; ++ks) {
            short8 a;
#pragma unroll
            for (int j = 0; j < 8; ++j) {
                int k = ks * 32 + lgrp * 8 + j;
                a[j] = (short)f2b(W[k * 128 + wc]);
            }
            wf[nt][ks] = a;
        }
    }

    const int nTiles = NR / 64;  // 625
    for (int tl = blockIdx.x; tl < nTiles; tl += gridDim.x) {
        const int rbase = tl * 64;
        {
            int r = t >> 3, c0 = (t & 7) * 16;
            const float4* h4 = (const float4*)(h + (size_t)(rbase + r) * 128 + c0);
            u32* HH = (u32*)(hH + r * S1 + c0);
            u32* HL = (u32*)(hL + r * S1 + c0);
#pragma unroll
            for (int q2 = 0; q2 < 4; ++q2) {
                float4 v = h4[q2];
                u16 h0 = f2b(v.x), h1 = f2b(v.y), h2 = f2b(v.z), h3 = f2b(v.w);
                HH[q2 * 2]     = (u32)h0 | ((u32)h1 << 16);
                HH[q2 * 2 + 1] = (u32)h2 | ((u32)h3 << 16);
                u16 l0 = f2b(v.x - b2f(h0)), l1 = f2b(v.y - b2f(h1));
                u16 l2 = f2b(v.z - b2f(h2)), l3 = f2b(v.w - b2f(h3));
                HL[q2 * 2]     = (u32)l0 | ((u32)l1 << 16);
                HL[q2 * 2 + 1] = (u32)l2 | ((u32)l3 << 16);
            }
        }
        __syncthreads();
#pragma unroll
        for (int mt = 0; mt < 4; ++mt) {
            short8 Hh[4], Hl[4];
#pragma unroll
            for (int ks = 0; ks < 4; ++ks) {
                const int off = (mt * 16 + lrow) * S1 + ks * 32 + lgrp * 8;
                Hh[ks] = *(const short8*)(hH + off);
                Hl[ks] = *(const short8*)(hL + off);
            }
#pragma unroll
            for (int nt = 0; nt < 4; ++nt) {
                f32x4 acc = {0.f, 0.f, 0.f, 0.f};
#pragma unroll
                for (int ks = 0; ks < 4; ++ks) {
                    acc = mfma16(Hh[ks], wf[nt][ks], acc);
                    acc = mfma16(Hl[ks], wf[nt][ks], acc);
                }
#pragma unroll
                for (int q = 0; q < 4; ++q) {
                    int r = rbase + mt * 16 + lgrp * 4 + q;
                    out[(size_t)r * 512 + wid * 64 + nt * 16 + lrow] = acc[q];
                }
            }
        }
        __syncthreads();
    }
}

// ---------------- kernel 2: attention edges via MFMA ----------------
// LDS-halved (scores reuse e-tile buffers); residual e carried in registers (no re-read).
// Epilogue gathers batched per M-tile for ILP. No VGPR pin beyond 128 (R3's 32-VGPR pin
// serialized the gather chains: occupancy 70% but dur regressed).
__global__ __launch_bounds__(512, 4) void k_attn(const float* __restrict__ e,
    const int* __restrict__ src, const int* __restrict__ dst,
    const float* __restrict__ We, const float* __restrict__ Oe_w, const float* __restrict__ Oe_b,
    const float* __restrict__ qkvqe, float* __restrict__ wV, float* __restrict__ z,
    float* __restrict__ stats, float* __restrict__ out_e)
{
    __shared__ __align__(16) u16 eH[64 * S1];   // e hi  -> reused as score hi
    __shared__ __align__(16) u16 eL[64 * S1];   // e lo  -> reused as score lo
    __shared__ int drowS[64], srowS[64];

    const int t = threadIdx.x;
    const int lane = t & 63;
    const int wid = t >> 6;          // wave id == head id (N-tile)
    const int lrow = lane & 15;
    const int lgrp = lane >> 4;
    const int c = wid * 16 + lrow;   // this lane's output channel

    short8 we8[4], oe8[4];
#pragma unroll
    for (int ks = 0; ks < 4; ++ks) {
        short8 a, b;
#pragma unroll
        for (int j = 0; j < 8; ++j) {
            int k = ks * 32 + lgrp * 8 + j;
            int idx = k * 128 + c;
            a[j] = (short)f2b(We[idx]);
            b[j] = (short)f2b(Oe_w[idx]);
        }
        we8[ks] = a; oe8[ks] = b;
    }
    const float oeb = Oe_b[c];
    float s1 = 0.f, s2 = 0.f;

    const int nTiles = ER / 64;  // 5000
    for (int tl = blockIdx.x; tl < nTiles; tl += gridDim.x) {
        const int rbase = tl * 64;
        {
            int r = t >> 3, c0 = (t & 7) * 16;
            int re = rbase + r, ei = re >> 2, p = re & 3;
            if ((t & 7) == 0) { drowS[r] = dst[ei] * 4 + p; srowS[r] = src[ei] * 4 + p; }
            const float4* ee4 = (const float4*)(e + (size_t)re * 128 + c0);
            u32* EH = (u32*)(eH + r * S1 + c0);
            u32* EL = (u32*)(eL + r * S1 + c0);
#pragma unroll
            for (int q2 = 0; q2 < 4; ++q2) {
                float4 ev = ee4[q2];
                u16 e0 = f2b(ev.x), e1 = f2b(ev.y), e2 = f2b(ev.z), e3 = f2b(ev.w);
                EH[q2 * 2]     = (u32)e0 | ((u32)e1 << 16);
                EH[q2 * 2 + 1] = (u32)e2 | ((u32)e3 << 16);
                u16 g0 = f2b(ev.x - b2f(e0)), g1 = f2b(ev.y - b2f(e1));
                u16 g2 = f2b(ev.z - b2f(e2)), g3 = f2b(ev.w - b2f(e3));
                EL[q2 * 2]     = (u32)g0 | ((u32)g1 << 16);
                EL[q2 * 2 + 1] = (u32)g2 | ((u32)g3 << 16);
            }
        }
        __syncthreads();

        // ---- phase 1 MFMA: pe for all 4 M-tiles into registers ----
        f32x4 ap0 = {0.f,0.f,0.f,0.f}, ap1 = {0.f,0.f,0.f,0.f};
        f32x4 ap2 = {0.f,0.f,0.f,0.f}, ap3 = {0.f,0.f,0.f,0.f};
#pragma unroll
        for (int ks = 0; ks < 4; ++ks) {
            const int boff = ks * 32 + lgrp * 8;
            ap0 = mfma16(*(const short8*)(eH + (0 * 16 + lrow) * S1 + boff), we8[ks], ap0);
            ap0 = mfma16(*(const short8*)(eL + (0 * 16 + lrow) * S1 + boff), we8[ks], ap0);
            ap1 = mfma16(*(const short8*)(eH + (1 * 16 + lrow) * S1 + boff), we8[ks], ap1);
            ap1 = mfma16(*(const short8*)(eL + (1 * 16 + lrow) * S1 + boff), we8[ks], ap1);
            ap2 = mfma16(*(const short8*)(eH + (2 * 16 + lrow) * S1 + boff), we8[ks], ap2);
            ap2 = mfma16(*(const short8*)(eL + (2 * 16 + lrow) * S1 + boff), we8[ks], ap2);
            ap3 = mfma16(*(const short8*)(eH + (3 * 16 + lrow) * S1 + boff), we8[ks], ap3);
            ap3 = mfma16(*(const short8*)(eL + (3 * 16 + lrow) * S1 + boff), we8[ks], ap3);
        }
        __syncthreads();   // all e-tile MFMA reads done; buffers may be overwritten

        // ---- epilogue 1: batched gathers, score, exp, atomics; scores -> eH/eL;
        //      residual e reconstructed to regs before overwrite ----
        float evr[16];
#pragma unroll
        for (int mt = 0; mt < 4; ++mt) {
            int dr4[4], sr4[4];
#pragma unroll
            for (int q = 0; q < 4; ++q) {
                int rr = mt * 16 + lgrp * 4 + q;
                dr4[q] = drowS[rr]; sr4[q] = srowS[rr];
            }
            float kg[4], qg[4], vg[4];
#pragma unroll
            for (int q = 0; q < 4; ++q) {
                kg[q] = qkvqe[(size_t)sr4[q] * 512 + 128 + c];
                qg[q] = qkvqe[(size_t)dr4[q] * 512 + c];
                vg[q] = qkvqe[(size_t)sr4[q] * 512 + 256 + c];
            }
            f32x4 ap = (mt == 0) ? ap0 : (mt == 1) ? ap1 : (mt == 2) ? ap2 : ap3;
#pragma unroll
            for (int q = 0; q < 4; ++q) {
                int rr = mt * 16 + lgrp * 4 + q;
                float scv = kg[q] * qg[q] * 0.25f + ap[q];
                float hs = scv;
                hs += __shfl_xor(hs, 1); hs += __shfl_xor(hs, 2);
                hs += __shfl_xor(hs, 4); hs += __shfl_xor(hs, 8);
                hs = fminf(fmaxf(hs, -5.f), 5.f);
                float sv = expf(hs);
                if (lrow == 0) atomicAdd(&z[dr4[q] * 8 + wid], sv);
                atomicAdd(&wV[(size_t)dr4[q] * 128 + c], vg[q] * sv);
                int off2 = rr * S1 + c;
                evr[mt * 4 + q] = b2f(eH[off2]) + b2f(eL[off2]);  // residual, before overwrite
                u16 shh = f2b(scv);
                eH[off2] = shh;
                eL[off2] = f2b(scv - b2f(shh));
            }
        }
        __syncthreads();

        // ---- phase 2: ef = e + Oe_b + sc @ Oe_w ----
#pragma unroll
        for (int mt = 0; mt < 4; ++mt) {
            f32x4 ao = {0.f, 0.f, 0.f, 0.f};
#pragma unroll
            for (int ks = 0; ks < 4; ++ks) {
                const int off = (mt * 16 + lrow) * S1 + ks * 32 + lgrp * 8;
                ao = mfma16(*(const short8*)(eH + off), oe8[ks], ao);
                ao = mfma16(*(const short8*)(eL + off), oe8[ks], ao);
            }
#pragma unroll
            for (int q = 0; q < 4; ++q) {
                int rr = mt * 16 + lgrp * 4 + q;
                int re = rbase + rr;
                float ef = evr[mt * 4 + q] + oeb + ao[q];
                out_e[(size_t)re * 128 + c] = ef;
                s1 += ef; s2 += ef * ef;
            }
        }
        __syncthreads();   // protect score buffers until next stage
    }
    atomicAdd(&stats[256 + c], s1);
    atomicAdd(&stats[384 + c], s2);
}

// ---------------- kernel 3: enhance edges via MFMA ----------------
__global__ __launch_bounds__(512) void k_enh(const float* __restrict__ h, const float* __restrict__ e,
    const int* __restrict__ src, const int* __restrict__ dst,
    const float* __restrict__ eWk, const float* __restrict__ eWv, const float* __restrict__ eWre,
    const float* __restrict__ qkvqe, float* __restrict__ henh)
{
    __shared__ __align__(16) u16 diffH[64 * S1];
    __shared__ __align__(16) u16 diffL[64 * S1];
    __shared__ __align__(16) u16 erH[64 * S1];
    __shared__ __align__(16) u16 erL[64 * S1];
    __shared__ int drowS[64];

    const int t = threadIdx.x;
    const int lane = t & 63;
    const int wid = t >> 6;          // wave id == head id (N-tile)
    const int lrow = lane & 15;
    const int lgrp = lane >> 4;

    short8 wkh[4], wkl[4], wv8[4], wre8[4];
#pragma unroll
    for (int ks = 0; ks < 4; ++ks) {
        short8 a, b, c2, d2;
#pragma unroll
        for (int j = 0; j < 8; ++j) {
            int k = ks * 32 + lgrp * 8 + j;
            int idx = k * 128 + wid * 16 + lrow;
            float wk = eWk[idx];
            u16 hh = f2b(wk);
            a[j]  = (short)hh;
            b[j]  = (short)f2b(wk - b2f(hh));
            c2[j] = (short)f2b(eWv[idx]);
            d2[j] = (short)f2b(eWre[idx]);
        }
        wkh[ks] = a; wkl[ks] = b; wv8[ks] = c2; wre8[ks] = d2;
    }

    const int nTiles = ER / 64;  // 5000
    for (int tl = blockIdx.x; tl < nTiles; tl += gridDim.x) {
        const int rbase = tl * 64;
        {
            int r = t >> 3, c0 = (t & 7) * 16;
            int re = rbase + r, ei = re >> 2, p = re & 3;
            int sr = src[ei] * 4 + p, dr = dst[ei] * 4 + p;
            if ((t & 7) == 0) drowS[r] = dr;
            const float4* hs4 = (const float4*)(h + (size_t)sr * 128 + c0);
            const float4* hd4 = (const float4*)(h + (size_t)dr * 128 + c0);
            const float4* ee4 = (const float4*)(e + (size_t)re * 128 + c0);
            u32* dH = (u32*)(diffH + r * S1 + c0);
            u32* dL = (u32*)(diffL + r * S1 + c0);
            u32* eH = (u32*)(erH + r * S1 + c0);
            u32* eL = (u32*)(erL + r * S1 + c0);
#pragma unroll
            for (int q2 = 0; q2 < 4; ++q2) {
                float4 a = hs4[q2], b = hd4[q2], ev = ee4[q2];
                float d0 = fmaxf(a.x - b.x, 0.f), d1 = fmaxf(a.y - b.y, 0.f);
                float d2 = fmaxf(a.z - b.z, 0.f), d3 = fmaxf(a.w - b.w, 0.f);
                u16 h0 = f2b(d0), h1 = f2b(d1), h2 = f2b(d2), h3 = f2b(d3);
                dH[q2 * 2]     = (u32)h0 | ((u32)h1 << 16);
                dH[q2 * 2 + 1] = (u32)h2 | ((u32)h3 << 16);
                u16 l0 = f2b(d0 - b2f(h0)), l1 = f2b(d1 - b2f(h1));
                u16 l2 = f2b(d2 - b2f(h2)), l3 = f2b(d3 - b2f(h3));
                dL[q2 * 2]     = (u32)l0 | ((u32)l1 << 16);
                dL[q2 * 2 + 1] = (u32)l2 | ((u32)l3 << 16);
                u16 e0 = f2b(ev.x), e1 = f2b(ev.y), e2 = f2b(ev.z), e3 = f2b(ev.w);
                eH[q2 * 2]     = (u32)e0 | ((u32)e1 << 16);
                eH[q2 * 2 + 1] = (u32)e2 | ((u32)e3 << 16);
                u16 g0 = f2b(ev.x - b2f(e0)), g1 = f2b(ev.y - b2f(e1));
                u16 g2 = f2b(ev.z - b2f(e2)), g3 = f2b(ev.w - b2f(e3));
                eL[q2 * 2]     = (u32)g0 | ((u32)g1 << 16);
                eL[q2 * 2 + 1] = (u32)g2 | ((u32)g3 << 16);
            }
        }
        __syncthreads();

#pragma unroll
        for (int mt = 0; mt < 4; ++mt) {
            f32x4 ak = {0.f, 0.f, 0.f, 0.f};
            f32x4 av = {0.f, 0.f, 0.f, 0.f};
            f32x4 ar = {0.f, 0.f, 0.f, 0.f};
#pragma unroll
            for (int ks = 0; ks < 4; ++ks) {
                const int off = (mt * 16 + lrow) * S1 + ks * 32 + lgrp * 8;
                short8 Ah = *(const short8*)(diffH + off);
                short8 Al = *(const short8*)(diffL + off);
                short8 Eh = *(const short8*)(erH + off);
                short8 El = *(const short8*)(erL + off);
                ak = mfma16(Ah, wkh[ks], ak);
                ak = mfma16(Al, wkh[ks], ak);
                ak = mfma16(Ah, wkl[ks], ak);
                av = mfma16(Ah, wv8[ks], av);
                av = mfma16(Al, wv8[ks], av);
                ar = mfma16(Eh, wre8[ks], ar);
                ar = mfma16(El, wre8[ks], ar);
            }
#pragma unroll
            for (int q = 0; q < 4; ++q) {
                int rr = mt * 16 + lgrp * 4 + q;
                int dr = drowS[rr];
                float qd = qkvqe[(size_t)dr * 512 + 384 + wid * 16 + lrow];
                float kd = ak[q];
                float sk = kd * kd;
                sk += __shfl_xor(sk, 1); sk += __shfl_xor(sk, 2);
                sk += __shfl_xor(sk, 4); sk += __shfl_xor(sk, 8);
                float sq = qd * qd;
                sq += __shfl_xor(sq, 1); sq += __shfl_xor(sq, 2);
                sq += __shfl_xor(sq, 4); sq += __shfl_xor(sq, 8);
                float nk = sqrtf(sk + 1e-12f);
                float nq = sqrtf(sq + 1e-12f);
                float sc = qd * kd * (nk * nq + 1e-6f) + ar[q];
                float msg = sc * av[q];
                atomicMaxF(&henh[(size_t)dr * 128 + wid * 16 + lrow], msg);
            }
        }
        __syncthreads();
    }
}

// ---------------- kernel 4: combine via MFMA: X = wV/z + henh_fix; hf = h + Oh_b + X@Oh_w ----
__global__ __launch_bounds__(512, 8) void k_comb(const float* __restrict__ h,
    const float* __restrict__ Oh_w, const float* __restrict__ Oh_b,
    const float* __restrict__ wV, const float* __restrict__ z, const float* __restrict__ henh,
    float* __restrict__ hf, float* __restrict__ stats)
{
    __shared__ __align__(16) u16 xH[64 * S1];
    __shared__ __align__(16) u16 xL[64 * S1];
    const int t = threadIdx.x;
    const int lane = t & 63;
    const int wid = t >> 6;
    const int lrow = lane & 15;
    const int lgrp = lane >> 4;
    const int c = wid * 16 + lrow;

    short8 oh8[4];
#pragma unroll
    for (int ks = 0; ks < 4; ++ks) {
        short8 a;
#pragma unroll
        for (int j = 0; j < 8; ++j) {
            int k = ks * 32 + lgrp * 8 + j;
            a[j] = (short)f2b(Oh_w[k * 128 + c]);
        }
        oh8[ks] = a;
    }
    const float ohb = Oh_b[c];
    float s1 = 0.f, s2 = 0.f;

    const int nTiles = NR / 64;  // 625
    for (int tl = blockIdx.x; tl < nTiles; tl += gridDim.x) {
        const int rbase = tl * 64;
        {
            int r = t >> 3, c0 = (t & 7) * 16;
            int gr = rbase + r;
            float zv = z[gr * 8 + (t & 7)] + 1e-6f;
            const float4* wv4 = (const float4*)(wV + (size_t)gr * 128 + c0);
            const float4* he4 = (const float4*)(henh + (size_t)gr * 128 + c0);
            u32* XH = (u32*)(xH + r * S1 + c0);
            u32* XL = (u32*)(xL + r * S1 + c0);
#pragma unroll
            for (int q2 = 0; q2 < 4; ++q2) {
                float4 a = wv4[q2], b = he4[q2];
                float x0, x1, x2, x3;
                {
                    u32 hb = __float_as_uint(b.x); float hv = (((hb >> 23) & 0xffu) == 0xffu) ? 0.f : b.x;
                    x0 = a.x / zv + hv;
                }
                {
                    u32 hb = __float_as_uint(b.y); float hv = (((hb >> 23) & 0xffu) == 0xffu) ? 0.f : b.y;
                    x1 = a.y / zv + hv;
                }
                {
                    u32 hb = __float_as_uint(b.z); float hv = (((hb >> 23) & 0xffu) == 0xffu) ? 0.f : b.z;
                    x2 = a.z / zv + hv;
                }
                {
                    u32 hb = __float_as_uint(b.w); float hv = (((hb >> 23) & 0xffu) == 0xffu) ? 0.f : b.w;
                    x3 = a.w / zv + hv;
                }
                u16 h0 = f2b(x0), h1 = f2b(x1), h2 = f2b(x2), h3 = f2b(x3);
                XH[q2 * 2]     = (u32)h0 | ((u32)h1 << 16);
                XH[q2 * 2 + 1] = (u32)h2 | ((u32)h3 << 16);
                u16 l0 = f2b(x0 - b2f(h0)), l1 = f2b(x1 - b2f(h1));
                u16 l2 = f2b(x2 - b2f(h2)), l3 = f2b(x3 - b2f(h3));
                XL[q2 * 2]     = (u32)l0 | ((u32)l1 << 16);
                XL[q2 * 2 + 1] = (u32)l2 | ((u32)l3 << 16);
            }
        }
        __syncthreads();
#pragma unroll
        for (int mt = 0; mt < 4; ++mt) {
            f32x4 acc = {0.f, 0.f, 0.f, 0.f};
#pragma unroll
            for (int ks = 0; ks < 4; ++ks) {
                const int off = (mt * 16 + lrow) * S1 + ks * 32 + lgrp * 8;
                acc = mfma16(*(const short8*)(xH + off), oh8[ks], acc);
                acc = mfma16(*(const short8*)(xL + off), oh8[ks], acc);
            }
#pragma unroll
            for (int q = 0; q < 4; ++q) {
                int r = rbase + mt * 16 + lgrp * 4 + q;
                float val = h[(size_t)r * 128 + c] + ohb + acc[q];
                hf[(size_t)r * 128 + c] = val;
                s1 += val; s2 += val * val;
            }
        }
        __syncthreads();
    }
    atomicAdd(&stats[c], s1);
    atomicAdd(&stats[128 + c], s2);
}

// ---------------- kernel 5: BN scale/shift prep ----------------
__global__ void k_bnprep(const float* __restrict__ stats,
    const float* __restrict__ gh, const float* __restrict__ bh,
    const float* __restrict__ ge, const float* __restrict__ be, float* __restrict__ bnsc)
{
    int c = threadIdx.x;
    if (c < 128) {
        float m = stats[c] / (float)NR;
        float v = stats[128 + c] / (float)NR - m * m;
        float sc = gh[c] * rsqrtf(v + 1e-5f);
        bnsc[c] = sc; bnsc[128 + c] = bh[c] - m * sc;
        m = stats[256 + c] / (float)ER;
        v = stats[384 + c] / (float)ER - m * m;
        sc = ge[c] * rsqrtf(v + 1e-5f);
        bnsc[256 + c] = sc; bnsc[384 + c] = be[c] - m * sc;
    }
}

// ---------------- kernel 6: BN-h apply + FFN + residual via MFMA -> out_h ----------------
// 32-row tiles. FF1: wave owns 32 of 256 cols (2 N-tiles); relu -> tt hi/lo LDS.
// FF2: wave owns 16 of 128 cols, K=256. Residual xn reconstructed from LDS hi/lo.
__global__ __launch_bounds__(512, 4) void k_ffn(const float* __restrict__ hf,
    const float* __restrict__ W1, const float* __restrict__ b1,
    const float* __restrict__ W2, const float* __restrict__ b2,
    const float* __restrict__ bnsc, float* __restrict__ out_h)
{
    __shared__ __align__(16) u16 xH[32 * S1];
    __shared__ __align__(16) u16 xL[32 * S1];
    __shared__ __align__(16) u16 tH[32 * S2];
    __shared__ __align__(16) u16 tL[32 * S2];
    __shared__ float scs[128], shs[128];
    const int t = threadIdx.x;
    const int lane = t & 63;
    const int wid = t >> 6;
    const int lrow = lane & 15;
    const int lgrp = lane >> 4;

    short8 w1f[2][4];
#pragma unroll
    for (int nt = 0; nt < 2; ++nt) {
        int col = wid * 32 + nt * 16 + lrow;
#pragma unroll
        for (int ks = 0; ks < 4; ++ks) {
            short8 a;
#pragma unroll
            for (int j = 0; j < 8; ++j) {
                int k = ks * 32 + lgrp * 8 + j;
                a[j] = (short)f2b(W1[k * 256 + col]);
            }
            w1f[nt][ks] = a;
        }
    }
    short8 w2f[8];
#pragma unroll
    for (int ks = 0; ks < 8; ++ks) {
        short8 a;
#pragma unroll
        for (int j = 0; j < 8; ++j) {
            int k = ks * 32 + lgrp * 8 + j;
            a[j] = (short)f2b(W2[k * 128 + wid * 16 + lrow]);
        }
        w2f[ks] = a;
    }
    const float bb1a = b1[wid * 32 + lrow];
    const float bb1b = b1[wid * 32 + 16 + lrow];
    const float bb2 = b2[wid * 16 + lrow];
    if (t < 128) { scs[t] = bnsc[t]; shs[t] = bnsc[128 + t]; }
    __syncthreads();

    const int nTiles = NR / 32;  // 1250
    for (int tl = blockIdx.x; tl < nTiles; tl += gridDim.x) {
        const int rbase = tl * 32;
        {
            int r = t >> 4, c0 = (t & 15) * 8;
            const float4* s4 = (const float4*)(hf + (size_t)(rbase + r) * 128 + c0);
            u32* XH = (u32*)(xH + r * S1 + c0);
            u32* XL = (u32*)(xL + r * S1 + c0);
#pragma unroll
            for (int q2 = 0; q2 < 2; ++q2) {
                float4 v = s4[q2];
                float x0 = v.x * scs[c0 + q2 * 4 + 0] + shs[c0 + q2 * 4 + 0];
                float x1 = v.y * scs[c0 + q2 * 4 + 1] + shs[c0 + q2 * 4 + 1];
                float x2 = v.z * scs[c0 + q2 * 4 + 2] + shs[c0 + q2 * 4 + 2];
                float x3 = v.w * scs[c0 + q2 * 4 + 3] + shs[c0 + q2 * 4 + 3];
                u16 h0 = f2b(x0), h1 = f2b(x1), h2 = f2b(x2), h3 = f2b(x3);
                XH[q2 * 2]     = (u32)h0 | ((u32)h1 << 16);
                XH[q2 * 2 + 1] = (u32)h2 | ((u32)h3 << 16);
                u16 l0 = f2b(x0 - b2f(h0)), l1 = f2b(x1 - b2f(h1));
                u16 l2 = f2b(x2 - b2f(h2)), l3 = f2b(x3 - b2f(h3));
                XL[q2 * 2]     = (u32)l0 | ((u32)l1 << 16);
                XL[q2 * 2 + 1] = (u32)l2 | ((u32)l3 << 16);
            }
        }
        __syncthreads();
        // FF1 + relu -> tt
#pragma unroll
        for (int mt = 0; mt < 2; ++mt) {
#pragma unroll
            for (int nt = 0; nt < 2; ++nt) {
                f32x4 acc = {0.f, 0.f, 0.f, 0.f};
#pragma unroll
                for (int ks = 0; ks < 4; ++ks) {
                    const int off = (mt * 16 + lrow) * S1 + ks * 32 + lgrp * 8;
                    acc = mfma16(*(const short8*)(xH + off), w1f[nt][ks], acc);
                    acc = mfma16(*(const short8*)(xL + off), w1f[nt][ks], acc);
                }
                float bb = nt ? bb1b : bb1a;
                int col = wid * 32 + nt * 16 + lrow;
#pragma unroll
                for (int q = 0; q < 4; ++q) {
                    int rr = mt * 16 + lgrp * 4 + q;
                    float tv = fmaxf(acc[q] + bb, 0.f);
                    u16 hh = f2b(tv);
                    tH[rr * S2 + col] = hh;
                    tL[rr * S2 + col] = f2b(tv - b2f(hh));
                }
            }
        }
        __syncthreads();
        // FF2 + residual
#pragma unroll
        for (int mt = 0; mt < 2; ++mt) {
            f32x4 acc = {0.f, 0.f, 0.f, 0.f};
#pragma unroll
            for (int ks = 0; ks < 8; ++ks) {
                const int off = (mt * 16 + lrow) * S2 + ks * 32 + lgrp * 8;
                acc = mfma16(*(const short8*)(tH + off), w2f[ks], acc);
                acc = mfma16(*(const short8*)(tL + off), w2f[ks], acc);
            }
            int c2 = wid * 16 + lrow;
#pragma unroll
            for (int q = 0; q < 4; ++q) {
                int rr = mt * 16 + lgrp * 4 + q;
                int offx = rr * S1 + c2;
                float xn = b2f(xH[offx]) + b2f(xL[offx]);
                float o = xn + bb2 + acc[q];
                out_h[(size_t)(rbase + rr) * 128 + c2] = o;
            }
        }
        __syncthreads();
    }
}

// ---------------- kernel 7: BN-e apply in place on d_out e-region (f32, float4) ----------------
__global__ __launch_bounds__(256) void k_bne(float* __restrict__ out_e, const float* __restrict__ bnsc)
{
    __shared__ float scs[128], shs[128];
    const int t = threadIdx.x;
    if (t < 128) { scs[t] = bnsc[256 + t]; shs[t] = bnsc[384 + t]; }
    __syncthreads();
    int idx = blockIdx.x * 256 + t;                // one float4 per thread
    const int total = ER * 128 / 4;                // 10,240,000
    for (; idx < total; idx += gridDim.x * 256) {
        float4 v = ((const float4*)out_e)[idx];
        int c0 = (idx * 4) & 127;
        v.x = v.x * scs[c0 + 0] + shs[c0 + 0];
        v.y = v.y * scs[c0 + 1] + shs[c0 + 1];
        v.z = v.z * scs[c0 + 2] + shs[c0 + 2];
        v.w = v.w * scs[c0 + 3] + shs[c0 + 3];
        ((float4*)out_e)[idx] = v;
    }
}

extern "C" void kernel_launch(void* const* d_in, const int* in_sizes, int n_in,
                              void* d_out, int out_size, void* d_ws, size_t ws_size,
                              hipStream_t stream)
{
    const float* h    = (const float*)d_in[0];
    const float* e    = (const float*)d_in[1];
    const int* src    = (const int*)d_in[2];
    const int* dst    = (const int*)d_in[3];
    const float* Wq   = (const float*)d_in[4];
    const float* Wk   = (const float*)d_in[5];
    const float* Wv   = (const float*)d_in[6];
    const float* We   = (const float*)d_in[7];
    const float* eWq  = (const float*)d_in[8];
    const float* eWk  = (const float*)d_in[9];
    const float* eWv  = (const float*)d_in[10];
    const float* eWre = (const float*)d_in[11];
    const float* Oh_w = (const float*)d_in[12];
    const float* Oh_b = (const float*)d_in[13];
    const float* Oe_w = (const float*)d_in[14];
    const float* Oe_b = (const float*)d_in[15];
    const float* bnhg = (const float*)d_in[16];
    const float* bnhb = (const float*)d_in[17];
    const float* bneg = (const float*)d_in[18];
    const float* bneb = (const float*)d_in[19];
    const float* W1   = (const float*)d_in[20];
    const float* b1   = (const float*)d_in[21];
    const float* W2   = (const float*)d_in[22];
    const float* b2   = (const float*)d_in[23];

    float* out_h = (float*)d_out;
    float* out_e = out_h + (size_t)NR * 128;

    char* w = (char*)d_ws;
    float* qkvqe = (float*)(w);                         // NR*512 f32  = 81,920,000 B
    float* wV    = (float*)(w + 81920000);              // NR*128 f32  = 20,480,000 B
    float* z     = (float*)(w + 102400000);             // NR*8  f32   =  1,280,000 B
    float* henh  = (float*)(w + 103680000);             // NR*128 f32  = 20,480,000 B
    float* hf    = (float*)(w + 124160000);             // NR*128 f32  = 20,480,000 B
    float* stats = (float*)(w + 144640000);             // 512 f32
    float* bnsc  = (float*)(w + 144642048);             // 512 f32

    hipMemsetAsync(wV,    0,    20480000, stream);
    hipMemsetAsync(z,     0,    1280000,  stream);
    hipMemsetAsync(stats, 0,    2048,     stream);
    hipMemsetAsync(henh,  0xFF, 20480000, stream);      // -NaN: identity for atomicMaxF, filtered by finite check

    k_qkvqe<<<625, 512, 0, stream>>>(h, Wq, Wk, Wv, eWq, qkvqe);
    k_attn <<<1024, 512, 0, stream>>>(e, src, dst, We, Oe_w, Oe_b, qkvqe, wV, z, stats, out_e);
    k_enh  <<<1024, 512, 0, stream>>>(h, e, src, dst, eWk, eWv, eWre, qkvqe, henh);
    k_comb <<<625, 512, 0, stream>>>(h, Oh_w, Oh_b, wV, z, henh, hf, stats);
    k_bnprep<<<1, 128, 0, stream>>>(stats, bnhg, bnhb, bneg, bneb, bnsc);
    k_ffn  <<<1250, 512, 0, stream>>>(hf, W1, b1, W2, b2, bnsc, out_h);
    k_bne  <<<2048, 256, 0, stream>>>(out_e, bnsc);
}

// Round 5
// 1474.834 us; speedup vs baseline: 2.8795x; 1.0723x over previous
//
#include <hip/hip_runtime.h>
#include <hip/hip_bf16.h>

#define NN 10000
#define NE 80000
#define PP 4
#define CC 128
#define NR (NN*PP)   // 40000 node rows
#define ER (NE*PP)   // 320000 edge rows
#define S1 136       // LDS row stride (u16) for bf16 K=128 rows: 68 dwords == 4 mod 32; 17 quads -> conflict-free b128
#define S2 264       // LDS row stride (u16) for K=256 rows: 132 dwords == 4 mod 32; 33 quads -> conflict-free b128

typedef unsigned short u16;
typedef unsigned int   u32;
typedef __attribute__((ext_vector_type(8))) short short8;   // 8 bf16 (4 VGPRs) MFMA A/B frag
typedef __attribute__((ext_vector_type(4))) float f32x4;    // MFMA C/D frag

__device__ inline float b2f(u16 v) { return __uint_as_float(((u32)v) << 16); }
__device__ inline u16 f2b(float f) {
    u32 x = __float_as_uint(f);
    return (u16)((x + 0x7fffu + ((x >> 16) & 1u)) >> 16);
}
__device__ inline void atomicMaxF(float* addr, float val) {
    if (val >= 0.f) atomicMax((int*)addr, __float_as_int(val));
    else            atomicMin((u32*)addr, __float_as_uint(val));
}
__device__ inline f32x4 mfma16(short8 a, short8 b, f32x4 c) {
    return __builtin_amdgcn_mfma_f32_16x16x32_bf16(a, b, c, 0, 0, 0);
}

// ---------------- kernel 1: [Q|K|V|Qe] = h @ [Wq|Wk|Wv|eWq] via MFMA, f32 out ----------------
__global__ __launch_bounds__(512) void k_qkvqe(const float* __restrict__ h,
    const float* __restrict__ Wq, const float* __restrict__ Wk,
    const float* __restrict__ Wv, const float* __restrict__ eWq,
    float* __restrict__ out)
{
    __shared__ __align__(16) u16 hH[64 * S1];
    __shared__ __align__(16) u16 hL[64 * S1];
    const int t = threadIdx.x;
    const int lane = t & 63;
    const int wid = t >> 6;
    const int lrow = lane & 15;
    const int lgrp = lane >> 4;

    short8 wf[4][4];
#pragma unroll
    for (int nt = 0; nt < 4; ++nt) {
        int col = wid * 64 + nt * 16 + lrow;
        int sel = col >> 7, wc = col & 127;
        const float* W = (sel == 0) ? Wq : (sel == 1) ? Wk : (sel == 2) ? Wv : eWq;
#pragma unroll
        for (int ks = 0; ks < 4; ++ks) {
            short8 a;
#pragma unroll
            for (int j = 0; j < 8; ++j) {
                int k = ks * 32 + lgrp * 8 + j;
                a[j] = (short)f2b(W[k * 128 + wc]);
            }
            wf[nt][ks] = a;
        }
    }

    const int nTiles = NR / 64;  // 625
    for (int tl = blockIdx.x; tl < nTiles; tl += gridDim.x) {
        const int rbase = tl * 64;
        {
            int r = t >> 3, c0 = (t & 7) * 16;
            const float4* h4 = (const float4*)(h + (size_t)(rbase + r) * 128 + c0);
            u32* HH = (u32*)(hH + r * S1 + c0);
            u32* HL = (u32*)(hL + r * S1 + c0);
#pragma unroll
            for (int q2 = 0; q2 < 4; ++q2) {
                float4 v = h4[q2];
                u16 h0 = f2b(v.x), h1 = f2b(v.y), h2 = f2b(v.z), h3 = f2b(v.w);
                HH[q2 * 2]     = (u32)h0 | ((u32)h1 << 16);
                HH[q2 * 2 + 1] = (u32)h2 | ((u32)h3 << 16);
                u16 l0 = f2b(v.x - b2f(h0)), l1 = f2b(v.y - b2f(h1));
                u16 l2 = f2b(v.z - b2f(h2)), l3 = f2b(v.w - b2f(h3));
                HL[q2 * 2]     = (u32)l0 | ((u32)l1 << 16);
                HL[q2 * 2 + 1] = (u32)l2 | ((u32)l3 << 16);
            }
        }
        __syncthreads();
#pragma unroll
        for (int mt = 0; mt < 4; ++mt) {
            short8 Hh[4], Hl[4];
#pragma unroll
            for (int ks = 0; ks < 4; ++ks) {
                const int off = (mt * 16 + lrow) * S1 + ks * 32 + lgrp * 8;
                Hh[ks] = *(const short8*)(hH + off);
                Hl[ks] = *(const short8*)(hL + off);
            }
#pragma unroll
            for (int nt = 0; nt < 4; ++nt) {
                f32x4 acc = {0.f, 0.f, 0.f, 0.f};
#pragma unroll
                for (int ks = 0; ks < 4; ++ks) {
                    acc = mfma16(Hh[ks], wf[nt][ks], acc);
                    acc = mfma16(Hl[ks], wf[nt][ks], acc);
                }
#pragma unroll
                for (int q = 0; q < 4; ++q) {
                    int r = rbase + mt * 16 + lgrp * 4 + q;
                    out[(size_t)r * 512 + wid * 64 + nt * 16 + lrow] = acc[q];
                }
            }
        }
        __syncthreads();
    }
}

// ---------------- kernel 2: FUSED edge kernel (attn path | enh path, block-parity split) ----
// Both paths are latency-bound alone (VALU ~11%, HBM ~15%, MFMA ~2.6% each). Even blocks run
// the attention body, odd blocks the enhance body; in-order dispatch co-resides one of each
// per CU so the attn gather/atomic epilogue hides under the enh MFMA/staging phases.
__global__ __launch_bounds__(512, 4) void k_edge(
    const float* __restrict__ h, const float* __restrict__ e,
    const int* __restrict__ src, const int* __restrict__ dst,
    const float* __restrict__ We, const float* __restrict__ Oe_w, const float* __restrict__ Oe_b,
    const float* __restrict__ eWk, const float* __restrict__ eWv, const float* __restrict__ eWre,
    const float* __restrict__ qkvqe, float* __restrict__ wV, float* __restrict__ z,
    float* __restrict__ stats, float* __restrict__ out_e, float* __restrict__ henh)
{
    __shared__ __align__(16) u16 bAH[64 * S1];   // attn: e hi -> score hi | enh: diff hi
    __shared__ __align__(16) u16 bAL[64 * S1];   // attn: e lo -> score lo | enh: diff lo
    __shared__ __align__(16) u16 bBH[64 * S1];   // enh: e hi
    __shared__ __align__(16) u16 bBL[64 * S1];   // enh: e lo
    __shared__ int drowS[64], srowS[64];

    const int t = threadIdx.x;
    const int lane = t & 63;
    const int wid = t >> 6;          // wave id == head id (N-tile)
    const int lrow = lane & 15;
    const int lgrp = lane >> 4;
    const int c = wid * 16 + lrow;   // this lane's output channel
    const int bstream = blockIdx.x >> 1;   // 0..999
    const int nTiles = ER / 64;            // 5000
    const int bstride = gridDim.x >> 1;    // 1000

    if ((blockIdx.x & 1) == 0) {
        // ================= ATTENTION PATH =================
        short8 we8[4], oe8[4];
#pragma unroll
        for (int ks = 0; ks < 4; ++ks) {
            short8 a, b;
#pragma unroll
            for (int j = 0; j < 8; ++j) {
                int k = ks * 32 + lgrp * 8 + j;
                int idx = k * 128 + c;
                a[j] = (short)f2b(We[idx]);
                b[j] = (short)f2b(Oe_w[idx]);
            }
            we8[ks] = a; oe8[ks] = b;
        }
        const float oeb = Oe_b[c];
        float s1 = 0.f, s2 = 0.f;

        for (int tl = bstream; tl < nTiles; tl += bstride) {
            const int rbase = tl * 64;
            {
                int r = t >> 3, c0 = (t & 7) * 16;
                int re = rbase + r, ei = re >> 2, p = re & 3;
                if ((t & 7) == 0) { drowS[r] = dst[ei] * 4 + p; srowS[r] = src[ei] * 4 + p; }
                const float4* ee4 = (const float4*)(e + (size_t)re * 128 + c0);
                u32* EH = (u32*)(bAH + r * S1 + c0);
                u32* EL = (u32*)(bAL + r * S1 + c0);
#pragma unroll
                for (int q2 = 0; q2 < 4; ++q2) {
                    float4 ev = ee4[q2];
                    u16 e0 = f2b(ev.x), e1 = f2b(ev.y), e2 = f2b(ev.z), e3 = f2b(ev.w);
                    EH[q2 * 2]     = (u32)e0 | ((u32)e1 << 16);
                    EH[q2 * 2 + 1] = (u32)e2 | ((u32)e3 << 16);
                    u16 g0 = f2b(ev.x - b2f(e0)), g1 = f2b(ev.y - b2f(e1));
                    u16 g2 = f2b(ev.z - b2f(e2)), g3 = f2b(ev.w - b2f(e3));
                    EL[q2 * 2]     = (u32)g0 | ((u32)g1 << 16);
                    EL[q2 * 2 + 1] = (u32)g2 | ((u32)g3 << 16);
                }
            }
            __syncthreads();

            // phase 1 MFMA: pe for all 4 M-tiles into registers
            f32x4 ap0 = {0.f,0.f,0.f,0.f}, ap1 = {0.f,0.f,0.f,0.f};
            f32x4 ap2 = {0.f,0.f,0.f,0.f}, ap3 = {0.f,0.f,0.f,0.f};
#pragma unroll
            for (int ks = 0; ks < 4; ++ks) {
                const int boff = ks * 32 + lgrp * 8;
                ap0 = mfma16(*(const short8*)(bAH + (0 * 16 + lrow) * S1 + boff), we8[ks], ap0);
                ap0 = mfma16(*(const short8*)(bAL + (0 * 16 + lrow) * S1 + boff), we8[ks], ap0);
                ap1 = mfma16(*(const short8*)(bAH + (1 * 16 + lrow) * S1 + boff), we8[ks], ap1);
                ap1 = mfma16(*(const short8*)(bAL + (1 * 16 + lrow) * S1 + boff), we8[ks], ap1);
                ap2 = mfma16(*(const short8*)(bAH + (2 * 16 + lrow) * S1 + boff), we8[ks], ap2);
                ap2 = mfma16(*(const short8*)(bAL + (2 * 16 + lrow) * S1 + boff), we8[ks], ap2);
                ap3 = mfma16(*(const short8*)(bAH + (3 * 16 + lrow) * S1 + boff), we8[ks], ap3);
                ap3 = mfma16(*(const short8*)(bAL + (3 * 16 + lrow) * S1 + boff), we8[ks], ap3);
            }
            __syncthreads();   // all e-tile MFMA reads done; buffers may be overwritten

            // epilogue 1: batched gathers, score, exp, atomics; scores -> bAH/bAL
            float evr[16];
#pragma unroll
            for (int mt = 0; mt < 4; ++mt) {
                int dr4[4], sr4[4];
#pragma unroll
                for (int q = 0; q < 4; ++q) {
                    int rr = mt * 16 + lgrp * 4 + q;
                    dr4[q] = drowS[rr]; sr4[q] = srowS[rr];
                }
                float kg[4], qg[4], vg[4];
#pragma unroll
                for (int q = 0; q < 4; ++q) {
                    kg[q] = qkvqe[(size_t)sr4[q] * 512 + 128 + c];
                    qg[q] = qkvqe[(size_t)dr4[q] * 512 + c];
                    vg[q] = qkvqe[(size_t)sr4[q] * 512 + 256 + c];
                }
                f32x4 ap = (mt == 0) ? ap0 : (mt == 1) ? ap1 : (mt == 2) ? ap2 : ap3;
#pragma unroll
                for (int q = 0; q < 4; ++q) {
                    int rr = mt * 16 + lgrp * 4 + q;
                    float scv = kg[q] * qg[q] * 0.25f + ap[q];
                    float hs = scv;
                    hs += __shfl_xor(hs, 1); hs += __shfl_xor(hs, 2);
                    hs += __shfl_xor(hs, 4); hs += __shfl_xor(hs, 8);
                    hs = fminf(fmaxf(hs, -5.f), 5.f);
                    float sv = expf(hs);
                    if (lrow == 0) atomicAdd(&z[dr4[q] * 8 + wid], sv);
                    atomicAdd(&wV[(size_t)dr4[q] * 128 + c], vg[q] * sv);
                    int off2 = rr * S1 + c;
                    evr[mt * 4 + q] = b2f(bAH[off2]) + b2f(bAL[off2]);  // residual, before overwrite
                    u16 shh = f2b(scv);
                    bAH[off2] = shh;
                    bAL[off2] = f2b(scv - b2f(shh));
                }
            }
            __syncthreads();

            // phase 2: ef = e + Oe_b + sc @ Oe_w
#pragma unroll
            for (int mt = 0; mt < 4; ++mt) {
                f32x4 ao = {0.f, 0.f, 0.f, 0.f};
#pragma unroll
                for (int ks = 0; ks < 4; ++ks) {
                    const int off = (mt * 16 + lrow) * S1 + ks * 32 + lgrp * 8;
                    ao = mfma16(*(const short8*)(bAH + off), oe8[ks], ao);
                    ao = mfma16(*(const short8*)(bAL + off), oe8[ks], ao);
                }
#pragma unroll
                for (int q = 0; q < 4; ++q) {
                    int rr = mt * 16 + lgrp * 4 + q;
                    int re = rbase + rr;
                    float ef = evr[mt * 4 + q] + oeb + ao[q];
                    out_e[(size_t)re * 128 + c] = ef;
                    s1 += ef; s2 += ef * ef;
                }
            }
            __syncthreads();
        }
        atomicAdd(&stats[256 + c], s1);
        atomicAdd(&stats[384 + c], s2);
    } else {
        // ================= ENHANCE PATH =================
        short8 wkh[4], wkl[4], wv8[4], wre8[4];
#pragma unroll
        for (int ks = 0; ks < 4; ++ks) {
            short8 a, b, c2, d2;
#pragma unroll
            for (int j = 0; j < 8; ++j) {
                int k = ks * 32 + lgrp * 8 + j;
                int idx = k * 128 + c;
                float wk = eWk[idx];
                u16 hh = f2b(wk);
                a[j]  = (short)hh;
                b[j]  = (short)f2b(wk - b2f(hh));
                c2[j] = (short)f2b(eWv[idx]);
                d2[j] = (short)f2b(eWre[idx]);
            }
            wkh[ks] = a; wkl[ks] = b; wv8[ks] = c2; wre8[ks] = d2;
        }

        for (int tl = bstream; tl < nTiles; tl += bstride) {
            const int rbase = tl * 64;
            {
                int r = t >> 3, c0 = (t & 7) * 16;
                int re = rbase + r, ei = re >> 2, p = re & 3;
                int sr = src[ei] * 4 + p, dr = dst[ei] * 4 + p;
                if ((t & 7) == 0) drowS[r] = dr;
                const float4* hs4 = (const float4*)(h + (size_t)sr * 128 + c0);
                const float4* hd4 = (const float4*)(h + (size_t)dr * 128 + c0);
                const float4* ee4 = (const float4*)(e + (size_t)re * 128 + c0);
                u32* dH = (u32*)(bAH + r * S1 + c0);
                u32* dL = (u32*)(bAL + r * S1 + c0);
                u32* eH = (u32*)(bBH + r * S1 + c0);
                u32* eL = (u32*)(bBL + r * S1 + c0);
#pragma unroll
                for (int q2 = 0; q2 < 4; ++q2) {
                    float4 a = hs4[q2], b = hd4[q2], ev = ee4[q2];
                    float d0 = fmaxf(a.x - b.x, 0.f), d1 = fmaxf(a.y - b.y, 0.f);
                    float d2 = fmaxf(a.z - b.z, 0.f), d3 = fmaxf(a.w - b.w, 0.f);
                    u16 h0 = f2b(d0), h1 = f2b(d1), h2 = f2b(d2), h3 = f2b(d3);
                    dH[q2 * 2]     = (u32)h0 | ((u32)h1 << 16);
                    dH[q2 * 2 + 1] = (u32)h2 | ((u32)h3 << 16);
                    u16 l0 = f2b(d0 - b2f(h0)), l1 = f2b(d1 - b2f(h1));
                    u16 l2 = f2b(d2 - b2f(h2)), l3 = f2b(d3 - b2f(h3));
                    dL[q2 * 2]     = (u32)l0 | ((u32)l1 << 16);
                    dL[q2 * 2 + 1] = (u32)l2 | ((u32)l3 << 16);
                    u16 e0 = f2b(ev.x), e1 = f2b(ev.y), e2 = f2b(ev.z), e3 = f2b(ev.w);
                    eH[q2 * 2]     = (u32)e0 | ((u32)e1 << 16);
                    eH[q2 * 2 + 1] = (u32)e2 | ((u32)e3 << 16);
                    u16 g0 = f2b(ev.x - b2f(e0)), g1 = f2b(ev.y - b2f(e1));
                    u16 g2 = f2b(ev.z - b2f(e2)), g3 = f2b(ev.w - b2f(e3));
                    eL[q2 * 2]     = (u32)g0 | ((u32)g1 << 16);
                    eL[q2 * 2 + 1] = (u32)g2 | ((u32)g3 << 16);
                }
            }
            __syncthreads();

#pragma unroll
            for (int mt = 0; mt < 4; ++mt) {
                f32x4 ak = {0.f, 0.f, 0.f, 0.f};
                f32x4 av = {0.f, 0.f, 0.f, 0.f};
                f32x4 ar = {0.f, 0.f, 0.f, 0.f};
#pragma unroll
                for (int ks = 0; ks < 4; ++ks) {
                    const int off = (mt * 16 + lrow) * S1 + ks * 32 + lgrp * 8;
                    short8 Ah = *(const short8*)(bAH + off);
                    short8 Al = *(const short8*)(bAL + off);
                    short8 Eh = *(const short8*)(bBH + off);
                    short8 El = *(const short8*)(bBL + off);
                    ak = mfma16(Ah, wkh[ks], ak);
                    ak = mfma16(Al, wkh[ks], ak);
                    ak = mfma16(Ah, wkl[ks], ak);
                    av = mfma16(Ah, wv8[ks], av);
                    av = mfma16(Al, wv8[ks], av);
                    ar = mfma16(Eh, wre8[ks], ar);
                    ar = mfma16(El, wre8[ks], ar);
                }
#pragma unroll
                for (int q = 0; q < 4; ++q) {
                    int rr = mt * 16 + lgrp * 4 + q;
                    int dr = drowS[rr];
                    float qd = qkvqe[(size_t)dr * 512 + 384 + c];
                    float kd = ak[q];
                    float sk = kd * kd;
                    sk += __shfl_xor(sk, 1); sk += __shfl_xor(sk, 2);
                    sk += __shfl_xor(sk, 4); sk += __shfl_xor(sk, 8);
                    float sq = qd * qd;
                    sq += __shfl_xor(sq, 1); sq += __shfl_xor(sq, 2);
                    sq += __shfl_xor(sq, 4); sq += __shfl_xor(sq, 8);
                    float nk = sqrtf(sk + 1e-12f);
                    float nq = sqrtf(sq + 1e-12f);
                    float sc = qd * kd * (nk * nq + 1e-6f) + ar[q];
                    float msg = sc * av[q];
                    atomicMaxF(&henh[(size_t)dr * 128 + c], msg);
                }
            }
            __syncthreads();
        }
    }
}

// ---------------- kernel 4: combine via MFMA: X = wV/z + henh_fix; hf = h + Oh_b + X@Oh_w ----
__global__ __launch_bounds__(512, 8) void k_comb(const float* __restrict__ h,
    const float* __restrict__ Oh_w, const float* __restrict__ Oh_b,
    const float* __restrict__ wV, const float* __restrict__ z, const float* __restrict__ henh,
    float* __restrict__ hf, float* __restrict__ stats)
{
    __shared__ __align__(16) u16 xH[64 * S1];
    __shared__ __align__(16) u16 xL[64 * S1];
    const int t = threadIdx.x;
    const int lane = t & 63;
    const int wid = t >> 6;
    const int lrow = lane & 15;
    const int lgrp = lane >> 4;
    const int c = wid * 16 + lrow;

    short8 oh8[4];
#pragma unroll
    for (int ks = 0; ks < 4; ++ks) {
        short8 a;
#pragma unroll
        for (int j = 0; j < 8; ++j) {
            int k = ks * 32 + lgrp * 8 + j;
            a[j] = (short)f2b(Oh_w[k * 128 + c]);
        }
        oh8[ks] = a;
    }
    const float ohb = Oh_b[c];
    float s1 = 0.f, s2 = 0.f;

    const int nTiles = NR / 64;  // 625
    for (int tl = blockIdx.x; tl < nTiles; tl += gridDim.x) {
        const int rbase = tl * 64;
        {
            int r = t >> 3, c0 = (t & 7) * 16;
            int gr = rbase + r;
            float zv = z[gr * 8 + (t & 7)] + 1e-6f;
            const float4* wv4 = (const float4*)(wV + (size_t)gr * 128 + c0);
            const float4* he4 = (const float4*)(henh + (size_t)gr * 128 + c0);
            u32* XH = (u32*)(xH + r * S1 + c0);
            u32* XL = (u32*)(xL + r * S1 + c0);
#pragma unroll
            for (int q2 = 0; q2 < 4; ++q2) {
                float4 a = wv4[q2], b = he4[q2];
                float x0, x1, x2, x3;
                {
                    u32 hb = __float_as_uint(b.x); float hv = (((hb >> 23) & 0xffu) == 0xffu) ? 0.f : b.x;
                    x0 = a.x / zv + hv;
                }
                {
                    u32 hb = __float_as_uint(b.y); float hv = (((hb >> 23) & 0xffu) == 0xffu) ? 0.f : b.y;
                    x1 = a.y / zv + hv;
                }
                {
                    u32 hb = __float_as_uint(b.z); float hv = (((hb >> 23) & 0xffu) == 0xffu) ? 0.f : b.z;
                    x2 = a.z / zv + hv;
                }
                {
                    u32 hb = __float_as_uint(b.w); float hv = (((hb >> 23) & 0xffu) == 0xffu) ? 0.f : b.w;
                    x3 = a.w / zv + hv;
                }
                u16 h0 = f2b(x0), h1 = f2b(x1), h2 = f2b(x2), h3 = f2b(x3);
                XH[q2 * 2]     = (u32)h0 | ((u32)h1 << 16);
                XH[q2 * 2 + 1] = (u32)h2 | ((u32)h3 << 16);
                u16 l0 = f2b(x0 - b2f(h0)), l1 = f2b(x1 - b2f(h1));
                u16 l2 = f2b(x2 - b2f(h2)), l3 = f2b(x3 - b2f(h3));
                XL[q2 * 2]     = (u32)l0 | ((u32)l1 << 16);
                XL[q2 * 2 + 1] = (u32)l2 | ((u32)l3 << 16);
            }
        }
        __syncthreads();
#pragma unroll
        for (int mt = 0; mt < 4; ++mt) {
            f32x4 acc = {0.f, 0.f, 0.f, 0.f};
#pragma unroll
            for (int ks = 0; ks < 4; ++ks) {
                const int off = (mt * 16 + lrow) * S1 + ks * 32 + lgrp * 8;
                acc = mfma16(*(const short8*)(xH + off), oh8[ks], acc);
                acc = mfma16(*(const short8*)(xL + off), oh8[ks], acc);
            }
#pragma unroll
            for (int q = 0; q < 4; ++q) {
                int r = rbase + mt * 16 + lgrp * 4 + q;
                float val = h[(size_t)r * 128 + c] + ohb + acc[q];
                hf[(size_t)r * 128 + c] = val;
                s1 += val; s2 += val * val;
            }
        }
        __syncthreads();
    }
    atomicAdd(&stats[c], s1);
    atomicAdd(&stats[128 + c], s2);
}

// ---------------- kernel 5: BN scale/shift prep ----------------
__global__ void k_bnprep(const float* __restrict__ stats,
    const float* __restrict__ gh, const float* __restrict__ bh,
    const float* __restrict__ ge, const float* __restrict__ be, float* __restrict__ bnsc)
{
    int c = threadIdx.x;
    if (c < 128) {
        float m = stats[c] / (float)NR;
        float v = stats[128 + c] / (float)NR - m * m;
        float sc = gh[c] * rsqrtf(v + 1e-5f);
        bnsc[c] = sc; bnsc[128 + c] = bh[c] - m * sc;
        m = stats[256 + c] / (float)ER;
        v = stats[384 + c] / (float)ER - m * m;
        sc = ge[c] * rsqrtf(v + 1e-5f);
        bnsc[256 + c] = sc; bnsc[384 + c] = be[c] - m * sc;
    }
}

// ---------------- kernel 6: BN-h apply + FFN + residual via MFMA -> out_h ----------------
__global__ __launch_bounds__(512, 4) void k_ffn(const float* __restrict__ hf,
    const float* __restrict__ W1, const float* __restrict__ b1,
    const float* __restrict__ W2, const float* __restrict__ b2,
    const float* __restrict__ bnsc, float* __restrict__ out_h)
{
    __shared__ __align__(16) u16 xH[32 * S1];
    __shared__ __align__(16) u16 xL[32 * S1];
    __shared__ __align__(16) u16 tH[32 * S2];
    __shared__ __align__(16) u16 tL[32 * S2];
    __shared__ float scs[128], shs[128];
    const int t = threadIdx.x;
    const int lane = t & 63;
    const int wid = t >> 6;
    const int lrow = lane & 15;
    const int lgrp = lane >> 4;

    short8 w1f[2][4];
#pragma unroll
    for (int nt = 0; nt < 2; ++nt) {
        int col = wid * 32 + nt * 16 + lrow;
#pragma unroll
        for (int ks = 0; ks < 4; ++ks) {
            short8 a;
#pragma unroll
            for (int j = 0; j < 8; ++j) {
                int k = ks * 32 + lgrp * 8 + j;
                a[j] = (short)f2b(W1[k * 256 + col]);
            }
            w1f[nt][ks] = a;
        }
    }
    short8 w2f[8];
#pragma unroll
    for (int ks = 0; ks < 8; ++ks) {
        short8 a;
#pragma unroll
        for (int j = 0; j < 8; ++j) {
            int k = ks * 32 + lgrp * 8 + j;
            a[j] = (short)f2b(W2[k * 128 + wid * 16 + lrow]);
        }
        w2f[ks] = a;
    }
    const float bb1a = b1[wid * 32 + lrow];
    const float bb1b = b1[wid * 32 + 16 + lrow];
    const float bb2 = b2[wid * 16 + lrow];
    if (t < 128) { scs[t] = bnsc[t]; shs[t] = bnsc[128 + t]; }
    __syncthreads();

    const int nTiles = NR / 32;  // 1250
    for (int tl = blockIdx.x; tl < nTiles; tl += gridDim.x) {
        const int rbase = tl * 32;
        {
            int r = t >> 4, c0 = (t & 15) * 8;
            const float4* s4 = (const float4*)(hf + (size_t)(rbase + r) * 128 + c0);
            u32* XH = (u32*)(xH + r * S1 + c0);
            u32* XL = (u32*)(xL + r * S1 + c0);
#pragma unroll
            for (int q2 = 0; q2 < 2; ++q2) {
                float4 v = s4[q2];
                float x0 = v.x * scs[c0 + q2 * 4 + 0] + shs[c0 + q2 * 4 + 0];
                float x1 = v.y * scs[c0 + q2 * 4 + 1] + shs[c0 + q2 * 4 + 1];
                float x2 = v.z * scs[c0 + q2 * 4 + 2] + shs[c0 + q2 * 4 + 2];
                float x3 = v.w * scs[c0 + q2 * 4 + 3] + shs[c0 + q2 * 4 + 3];
                u16 h0 = f2b(x0), h1 = f2b(x1), h2 = f2b(x2), h3 = f2b(x3);
                XH[q2 * 2]     = (u32)h0 | ((u32)h1 << 16);
                XH[q2 * 2 + 1] = (u32)h2 | ((u32)h3 << 16);
                u16 l0 = f2b(x0 - b2f(h0)), l1 = f2b(x1 - b2f(h1));
                u16 l2 = f2b(x2 - b2f(h2)), l3 = f2b(x3 - b2f(h3));
                XL[q2 * 2]     = (u32)l0 | ((u32)l1 << 16);
                XL[q2 * 2 + 1] = (u32)l2 | ((u32)l3 << 16);
            }
        }
        __syncthreads();
        // FF1 + relu -> tt
#pragma unroll
        for (int mt = 0; mt < 2; ++mt) {
#pragma unroll
            for (int nt = 0; nt < 2; ++nt) {
                f32x4 acc = {0.f, 0.f, 0.f, 0.f};
#pragma unroll
                for (int ks = 0; ks < 4; ++ks) {
                    const int off = (mt * 16 + lrow) * S1 + ks * 32 + lgrp * 8;
                    acc = mfma16(*(const short8*)(xH + off), w1f[nt][ks], acc);
                    acc = mfma16(*(const short8*)(xL + off), w1f[nt][ks], acc);
                }
                float bb = nt ? bb1b : bb1a;
                int col = wid * 32 + nt * 16 + lrow;
#pragma unroll
                for (int q = 0; q < 4; ++q) {
                    int rr = mt * 16 + lgrp * 4 + q;
                    float tv = fmaxf(acc[q] + bb, 0.f);
                    u16 hh = f2b(tv);
                    tH[rr * S2 + col] = hh;
                    tL[rr * S2 + col] = f2b(tv - b2f(hh));
                }
            }
        }
        __syncthreads();
        // FF2 + residual
#pragma unroll
        for (int mt = 0; mt < 2; ++mt) {
            f32x4 acc = {0.f, 0.f, 0.f, 0.f};
#pragma unroll
            for (int ks = 0; ks < 8; ++ks) {
                const int off = (mt * 16 + lrow) * S2 + ks * 32 + lgrp * 8;
                acc = mfma16(*(const short8*)(tH + off), w2f[ks], acc);
                acc = mfma16(*(const short8*)(tL + off), w2f[ks], acc);
            }
            int c2 = wid * 16 + lrow;
#pragma unroll
            for (int q = 0; q < 4; ++q) {
                int rr = mt * 16 + lgrp * 4 + q;
                int offx = rr * S1 + c2;
                float xn = b2f(xH[offx]) + b2f(xL[offx]);
                float o = xn + bb2 + acc[q];
                out_h[(size_t)(rbase + rr) * 128 + c2] = o;
            }
        }
        __syncthreads();
    }
}

// ---------------- kernel 7: BN-e apply in place on d_out e-region (f32, float4) ----------------
__global__ __launch_bounds__(256) void k_bne(float* __restrict__ out_e, const float* __restrict__ bnsc)
{
    __shared__ float scs[128], shs[128];
    const int t = threadIdx.x;
    if (t < 128) { scs[t] = bnsc[256 + t]; shs[t] = bnsc[384 + t]; }
    __syncthreads();
    int idx = blockIdx.x * 256 + t;                // one float4 per thread
    const int total = ER * 128 / 4;                // 10,240,000
    for (; idx < total; idx += gridDim.x * 256) {
        float4 v = ((const float4*)out_e)[idx];
        int c0 = (idx * 4) & 127;
        v.x = v.x * scs[c0 + 0] + shs[c0 + 0];
        v.y = v.y * scs[c0 + 1] + shs[c0 + 1];
        v.z = v.z * scs[c0 + 2] + shs[c0 + 2];
        v.w = v.w * scs[c0 + 3] + shs[c0 + 3];
        ((float4*)out_e)[idx] = v;
    }
}

extern "C" void kernel_launch(void* const* d_in, const int* in_sizes, int n_in,
                              void* d_out, int out_size, void* d_ws, size_t ws_size,
                              hipStream_t stream)
{
    const float* h    = (const float*)d_in[0];
    const float* e    = (const float*)d_in[1];
    const int* src    = (const int*)d_in[2];
    const int* dst    = (const int*)d_in[3];
    const float* Wq   = (const float*)d_in[4];
    const float* Wk   = (const float*)d_in[5];
    const float* Wv   = (const float*)d_in[6];
    const float* We   = (const float*)d_in[7];
    const float* eWq  = (const float*)d_in[8];
    const float* eWk  = (const float*)d_in[9];
    const float* eWv  = (const float*)d_in[10];
    const float* eWre = (const float*)d_in[11];
    const float* Oh_w = (const float*)d_in[12];
    const float* Oh_b = (const float*)d_in[13];
    const float* Oe_w = (const float*)d_in[14];
    const float* Oe_b = (const float*)d_in[15];
    const float* bnhg = (const float*)d_in[16];
    const float* bnhb = (const float*)d_in[17];
    const float* bneg = (const float*)d_in[18];
    const float* bneb = (const float*)d_in[19];
    const float* W1   = (const float*)d_in[20];
    const float* b1   = (const float*)d_in[21];
    const float* W2   = (const float*)d_in[22];
    const float* b2   = (const float*)d_in[23];

    float* out_h = (float*)d_out;
    float* out_e = out_h + (size_t)NR * 128;

    char* w = (char*)d_ws;
    float* qkvqe = (float*)(w);                         // NR*512 f32  = 81,920,000 B
    float* wV    = (float*)(w + 81920000);              // NR*128 f32  = 20,480,000 B
    float* z     = (float*)(w + 102400000);             // NR*8  f32   =  1,280,000 B
    float* henh  = (float*)(w + 103680000);             // NR*128 f32  = 20,480,000 B
    float* hf    = (float*)(w + 124160000);             // NR*128 f32  = 20,480,000 B
    float* stats = (float*)(w + 144640000);             // 512 f32
    float* bnsc  = (float*)(w + 144642048);             // 512 f32

    hipMemsetAsync(wV,    0,    20480000, stream);
    hipMemsetAsync(z,     0,    1280000,  stream);
    hipMemsetAsync(stats, 0,    2048,     stream);
    hipMemsetAsync(henh,  0xFF, 20480000, stream);      // -NaN: identity for atomicMaxF, filtered by finite check

    k_qkvqe<<<625, 512, 0, stream>>>(h, Wq, Wk, Wv, eWq, qkvqe);
    k_edge <<<2000, 512, 0, stream>>>(h, e, src, dst, We, Oe_w, Oe_b, eWk, eWv, eWre,
                                      qkvqe, wV, z, stats, out_e, henh);
    k_comb <<<625, 512, 0, stream>>>(h, Oh_w, Oh_b, wV, z, henh, hf, stats);
    k_bnprep<<<1, 128, 0, stream>>>(stats, bnhg, bnhb, bneg, bneb, bnsc);
    k_ffn  <<<1250, 512, 0, stream>>>(hf, W1, b1, W2, b2, bnsc, out_h);
    k_bne  <<<2048, 256, 0, stream>>>(out_e, bnsc);
}